// Round 12
// baseline (6115.668 us; speedup 1.0000x reference)
//
#include <hip/hip_runtime.h>

// DecoderRNN: 3-layer LSTM (H=1024) + fc, B=256, 128 steps, constant input.
// bf16 MFMA 16x16x32; gate-interleaved weight columns; persistent plain-launch
// kernel with software grid barrier (release-only fence; h-state via
// device-coherent loads).  Base = R8 structure (fastest: 40us/step).
// THIS ROUND: (1) NT (no-L2-allocate) loads for 3 of 8 weight stripes per XCD
// -> remaining 3.2MB weights stay L2-resident instead of 5.1MB cyclic thrash;
// (2) parallel 8-lane barrier poll in root block (was 8 serial MALL trips).

#define DEVINL static __device__ __forceinline__

typedef __bf16 bf16x8 __attribute__((ext_vector_type(8)));
typedef float f32x4 __attribute__((ext_vector_type(4)));
typedef unsigned short u16;
typedef unsigned int u32;
typedef unsigned long long u64;

DEVINL u16 f2bf(float f) {
  u32 u = __builtin_bit_cast(u32, f);
  u += 0x7fffu + ((u >> 16) & 1u);  // RNE
  return (u16)(u >> 16);
}
DEVINL float bf2f(u16 h) {
  u32 u = (u32)h << 16;
  return __builtin_bit_cast(float, u);
}
DEVINL float sigm(float x) { return 1.0f / (1.0f + __expf(-x)); }
DEVINL float tanhfast(float x) { return 1.0f - 2.0f / (1.0f + __expf(2.0f * x)); }

// device-coherent global->LDS (h-state: written by other XCDs, read via MALL)
DEVINL void glds_coh(const u16* g, u16* l) {
  __builtin_amdgcn_global_load_lds(
      (const __attribute__((address_space(1))) u32*)g,
      (__attribute__((address_space(3))) u32*)l, 16, 0, 17);  // sc0|sc1
}
// cached global->LDS (resident weight stripes: stay in per-XCD L2)
DEVINL void glds_w(const u16* g, u16* l) {
  __builtin_amdgcn_global_load_lds(
      (const __attribute__((address_space(1))) u32*)g,
      (__attribute__((address_space(3))) u32*)l, 16, 0, 0);
}
// non-temporal global->LDS (streaming weight stripes: don't evict residents)
DEVINL void glds_wnt(const u16* g, u16* l) {
  __builtin_amdgcn_global_load_lds(
      (const __attribute__((address_space(1))) u32*)g,
      (__attribute__((address_space(3))) u32*)l, 16, 0, 2);  // NT
}

// permuted column index -> original gate column: P = grp*64 + g*16 + jj
DEVINL int permcol(int P) {
  int grp = P >> 6, g = (P >> 4) & 3, jj = P & 15;
  return g * 1024 + grp * 16 + jj;
}

struct Params {
  const float* fc_b;
  const float* inh_b;
  const float* inc_b;
  const u16 *WT0, *WT1, *WT2, *WT00, *FCW, *WIH, *WIC, *FRB;
  u16* HB;   // h state bf16: [layer][parity][256][1024]  (1<<18 u16 per buf)
  u16* G0P;  // precomputed layer0 input gates, bf16 [256][4096]
  float *G0B, *B1P, *B2P, *CC;  // CC: c state fp32 [layer][256][1024]
  float* out;
};

#define MODE_L0 0
#define MODE_L 1
#define MODE_FC 2
#define MODE_G0 3
#define MODE_H 4
#define MODE_C 5

// one 64-K tile: per thread 4 A-loads (coherent) + 2 B-loads (cached or NT),
// direct to LDS. Source-side XOR swizzle (granule ^ row&7); LDS dest linear.
DEVINL void issue_tile(int kt, const u16* A0, const u16* A1, int kSplit, int sA,
                       int K, const u16* Wt, int m0, int wrow,
                       const int (&rq)[4], const int (&kqs)[4],
                       const int (&lo)[4], u16* Abuf, u16* Bbuf, int nt) {
  const u16* Ab = (kt < kSplit) ? (A0 + kt) : (A1 + (kt - kSplit));
#pragma unroll
  for (int q = 0; q < 4; ++q)
    glds_coh(Ab + (size_t)(m0 + rq[q]) * sA + kqs[q] * 8, Abuf + lo[q]);
  const u16* Bb = Wt + kt;
  if (nt) {
#pragma unroll
    for (int q = 0; q < 2; ++q)
      glds_wnt(Bb + (size_t)(wrow + rq[q]) * K + kqs[q] * 8, Bbuf + lo[q]);
  } else {
#pragma unroll
    for (int q = 0; q < 2; ++q)
      glds_w(Bb + (size_t)(wrow + rq[q]) * K + kqs[q] * 8, Bbuf + lo[q]);
  }
}

DEVINL void mfma_tile(const u16* Al, const u16* Bl, f32x4 (&acc)[2][4], int rl0,
                      int hh, int e7, int jj) {
#pragma unroll
  for (int kk = 0; kk < 2; ++kk) {
    int sl = (((kk << 2) | hh) ^ e7) * 8;
    bf16x8 a0 = *(const bf16x8*)(Al + rl0 * 64 + sl);
    bf16x8 a1 = *(const bf16x8*)(Al + (rl0 + 16) * 64 + sl);
    bf16x8 b0 = *(const bf16x8*)(Bl + (jj)*64 + sl);
    bf16x8 b1 = *(const bf16x8*)(Bl + (16 + jj) * 64 + sl);
    bf16x8 b2 = *(const bf16x8*)(Bl + (32 + jj) * 64 + sl);
    bf16x8 b3 = *(const bf16x8*)(Bl + (48 + jj) * 64 + sl);
    acc[0][0] = __builtin_amdgcn_mfma_f32_16x16x32_bf16(a0, b0, acc[0][0], 0, 0, 0);
    acc[0][1] = __builtin_amdgcn_mfma_f32_16x16x32_bf16(a0, b1, acc[0][1], 0, 0, 0);
    acc[0][2] = __builtin_amdgcn_mfma_f32_16x16x32_bf16(a0, b2, acc[0][2], 0, 0, 0);
    acc[0][3] = __builtin_amdgcn_mfma_f32_16x16x32_bf16(a0, b3, acc[0][3], 0, 0, 0);
    acc[1][0] = __builtin_amdgcn_mfma_f32_16x16x32_bf16(a1, b0, acc[1][0], 0, 0, 0);
    acc[1][1] = __builtin_amdgcn_mfma_f32_16x16x32_bf16(a1, b1, acc[1][1], 0, 0, 0);
    acc[1][2] = __builtin_amdgcn_mfma_f32_16x16x32_bf16(a1, b2, acc[1][2], 0, 0, 0);
    acc[1][3] = __builtin_amdgcn_mfma_f32_16x16x32_bf16(a1, b3, acc[1][3], 0, 0, 0);
  }
}

// Block: 256 threads = 4 waves, output tile 128(M) x 64(N); wave w = rows
// [w*32, w*32+32): 2 M-frags x 4 N-frags. LDS double-buffered.
// Counted vmcnt(6): next tile's 6 loads stay in flight across both barriers.
template <int MODE>
DEVINL void mm_body(u16* Al, u16* Bl, const u16* A0, const u16* A1, int sA,
                    int kSplit, int K, const u16* Wt, int m0, int bn, int t,
                    const u16* Gfull, const float* biasP, float* Cst, u16* Hout,
                    float* outp, int nt) {
  const int tid = threadIdx.x;
  const int l = tid & 63;
  const int w = tid >> 6;
  const int hh = (l >> 4) & 3;
  const int jj = l & 15;
  const int rl0 = w * 32 + jj;
  const int e7 = l & 7;

  int rq[4], kqs[4], lo[4];
#pragma unroll
  for (int q = 0; q < 4; ++q) {
    int L = tid + q * 256;
    rq[q] = L >> 3;
    kqs[q] = (L & 7) ^ (rq[q] & 7);       // source-swizzled granule
    lo[q] = ((tid & ~63) + q * 256) * 8;  // wave-uniform LDS base (u16 units)
  }

  f32x4 acc[2][4];
#pragma unroll
  for (int m = 0; m < 2; ++m)
#pragma unroll
    for (int g = 0; g < 4; ++g) acc[m][g] = (f32x4){0.f, 0.f, 0.f, 0.f};

  const int wrow = bn * 64;
  const int n = K >> 6;  // 64-K tiles

  issue_tile(0, A0, A1, kSplit, sA, K, Wt, m0, wrow, rq, kqs, lo, Al, Bl, nt);
  issue_tile(64, A0, A1, kSplit, sA, K, Wt, m0, wrow, rq, kqs, lo, Al + 8192,
             Bl + 4096, nt);

  for (int j = 0; j < n; ++j) {
    u16* Ac = Al + (j & 1) * 8192;
    u16* Bc = Bl + (j & 1) * 4096;
    if (j < n - 1)
      asm volatile("s_waitcnt vmcnt(6)" ::: "memory");
    else
      asm volatile("s_waitcnt vmcnt(0)" ::: "memory");
    __builtin_amdgcn_s_barrier();
    __builtin_amdgcn_sched_barrier(0);
    mfma_tile(Ac, Bc, acc, rl0, hh, e7, jj);
    __builtin_amdgcn_sched_barrier(0);
    __builtin_amdgcn_s_barrier();
    if (j + 2 < n)
      issue_tile((j + 2) * 64, A0, A1, kSplit, sA, K, Wt, m0, wrow, rq, kqs, lo,
                 Ac, Bc, nt);
  }

  // C/D layout: col = lane&15, row = (lane>>4)*4 + reg  [m89-verified]
  const int rb = m0 + w * 32 + (hh << 2);
  if (MODE <= MODE_L) {
    float add0 = 0.f, add1 = 0.f, add2 = 0.f, add3 = 0.f;
    if (MODE == MODE_L) {
      add0 = biasP[bn * 64 + jj];
      add1 = biasP[bn * 64 + 16 + jj];
      add2 = biasP[bn * 64 + 32 + jj];
      add3 = biasP[bn * 64 + 48 + jj];
    }
    const int j = bn * 16 + jj;  // hidden unit
#pragma unroll
    for (int m = 0; m < 2; ++m) {
#pragma unroll
      for (int r = 0; r < 4; ++r) {
        int b = rb + m * 16 + r;
        float g0v, g1v, g2v, g3v;
        if (MODE == MODE_L0) {
          const u16* G = Gfull + (size_t)b * 4096 + bn * 64 + jj;
          g0v = acc[m][0][r] + bf2f(G[0]);
          g1v = acc[m][1][r] + bf2f(G[16]);
          g2v = acc[m][2][r] + bf2f(G[32]);
          g3v = acc[m][3][r] + bf2f(G[48]);
        } else {
          g0v = acc[m][0][r] + add0;
          g1v = acc[m][1][r] + add1;
          g2v = acc[m][2][r] + add2;
          g3v = acc[m][3][r] + add3;
        }
        float iv = sigm(g0v), fv = sigm(g1v), gv = tanhfast(g2v), ov = sigm(g3v);
        size_t ci = (size_t)b * 1024 + j;
        float cn = fv * Cst[ci] + iv * gv;
        Cst[ci] = cn;
        Hout[ci] = f2bf(ov * tanhfast(cn));
      }
    }
  } else if (MODE == MODE_FC) {
#pragma unroll
    for (int g = 0; g < 4; ++g) {
      int nn = bn * 64 + g * 16 + jj;
      if (nn < 204) {
        float bv2 = biasP[nn];
#pragma unroll
        for (int m = 0; m < 2; ++m)
#pragma unroll
          for (int r = 0; r < 4; ++r) {
            int b = rb + m * 16 + r;
            outp[((size_t)b * 128 + t) * 204 + nn] = acc[m][g][r] + bv2;
          }
      }
    }
  } else if (MODE == MODE_G0) {
#pragma unroll
    for (int g = 0; g < 4; ++g) {
      int P = bn * 64 + g * 16 + jj;
      float bv2 = biasP[P];
#pragma unroll
      for (int m = 0; m < 2; ++m)
#pragma unroll
        for (int r = 0; r < 4; ++r) {
          int b = rb + m * 16 + r;
          Hout[(size_t)b * 4096 + P] = f2bf(acc[m][g][r] + bv2);
        }
    }
  } else {  // MODE_H / MODE_C : init states, cols are orig n = lay*1024 + j
#pragma unroll
    for (int g = 0; g < 4; ++g) {
      int nn = bn * 64 + g * 16 + jj;
      int lay = nn >> 10, j2 = nn & 1023;
      float bv2 = biasP[nn];
#pragma unroll
      for (int m = 0; m < 2; ++m)
#pragma unroll
        for (int r = 0; r < 4; ++r) {
          int b = rb + m * 16 + r;
          float v = acc[m][g][r] + bv2;
          if (MODE == MODE_H)
            Hout[(size_t)((lay * 2 + 1) * 256 + b) * 1024 + j2] = f2bf(v);
          else
            outp[(size_t)(lay * 256 + b) * 1024 + j2] = v;
        }
    }
  }
}

// Grid barrier: release fence (writeback dirty h lines, no inval -> resident
// weights stay cached) + two-level counter/flag. Root block polls all 8 group
// counters IN PARALLEL (lanes 0..7) instead of serially.
DEVINL void grid_barrier(u32* bar, int bid, int ep) {
  __syncthreads();
  const int tid = threadIdx.x;
  if (bid == 0) {
    if (tid == 0) {
      __builtin_amdgcn_fence(__ATOMIC_RELEASE, "agent");
      __hip_atomic_fetch_add(bar, 1u, __ATOMIC_RELAXED,
                             __HIP_MEMORY_SCOPE_AGENT);
    }
    if (tid < 8) {
#pragma unroll 1
      while (__hip_atomic_load(bar + tid * 64, __ATOMIC_RELAXED,
                               __HIP_MEMORY_SCOPE_AGENT) < (u32)ep * 49u)
        __builtin_amdgcn_s_sleep(4);
    }
    __syncthreads();
    if (tid == 0)
      __hip_atomic_store(bar + 512, (u32)ep, __ATOMIC_RELAXED,
                         __HIP_MEMORY_SCOPE_AGENT);
  } else if (tid == 0) {
    __builtin_amdgcn_fence(__ATOMIC_RELEASE, "agent");
    __hip_atomic_fetch_add(bar + (bid & 7) * 64, 1u, __ATOMIC_RELAXED,
                           __HIP_MEMORY_SCOPE_AGENT);
#pragma unroll 1
    while (__hip_atomic_load(bar + 512, __ATOMIC_RELAXED,
                             __HIP_MEMORY_SCOPE_AGENT) < (u32)ep)
      __builtin_amdgcn_s_sleep(8);
  }
  __syncthreads();
}

// Persistent pipelined kernel, PLAIN launch; 392 blocks co-resident:
// LDS 48KB -> 3 blocks/CU; launch_bounds(256,2) -> VGPR<=128 -> >=2/CU;
// 392 <= 512. bid&7 ~ XCD affinity (bn>>3 == bid&7) and barrier group (49).
// NT weight streaming for local stripes 5..7 (1.9MB/XCD/step); stripes 0..4
// (3.2MB/XCD) stay L2-resident across all 131 steps.
__global__ __launch_bounds__(256, 2) void persist_kernel(Params p, u32* bar) {
  __shared__ u16 Al[2 * 128 * 64];  // 32KB
  __shared__ u16 Bl[2 * 64 * 64];   // 16KB
  const int bid = blockIdx.x;
  int job, mb, bn;
  if (bid < 384) {
    job = bid >> 7;
    int r = bid & 127;
    bn = (r & 7) * 8 + (r >> 4);  // bn>>3 == bid&7 (XCD-affine weight slice)
    mb = (r >> 3) & 1;
  } else {
    job = 3;
    int r = bid - 384;
    mb = r >> 2;
    bn = r & 3;
  }
  const int nt = (bid < 384) && ((bn & 7) >= 5);
  u16* HB = p.HB;
#define HBP(lay, pp) (HB + (size_t)(((lay)*2 + (pp)) << 18))
  for (int i = 0; i <= 130; ++i) {
    int t = i - job;
    if ((unsigned)t < 128u) {
      int par = t & 1, pv = par ^ 1;
      if (job == 0) {
        mm_body<MODE_L0>(Al, Bl, HBP(0, pv), nullptr, 1024, 1 << 30, 1024,
                         p.WT0, mb * 128, bn, t, p.G0P, nullptr, p.CC,
                         HBP(0, par), nullptr, nt);
      } else if (job == 1) {
        mm_body<MODE_L>(Al, Bl, HBP(0, par), HBP(1, pv), 1024, 1024, 2048,
                        p.WT1, mb * 128, bn, t, nullptr, p.B1P,
                        p.CC + (size_t)256 * 1024, HBP(1, par), nullptr, nt);
      } else if (job == 2) {
        mm_body<MODE_L>(Al, Bl, HBP(1, par), HBP(2, pv), 1024, 1024, 2048,
                        p.WT2, mb * 128, bn, t, nullptr, p.B2P,
                        p.CC + (size_t)512 * 1024, HBP(2, par), nullptr, nt);
      } else {
        mm_body<MODE_FC>(Al, Bl, HBP(2, par), nullptr, 1024, 1 << 30, 1024,
                         p.FCW, mb * 128, bn, t, nullptr, p.fc_b, nullptr,
                         nullptr, p.out, nt);
      }
    }
    if (i < 130) grid_barrier(bar, bid, i + 1);
  }
#undef HBP
}

// one-time: G0 = x_in@W_ih0+biases (permuted), h/c init = frame@in{h,c}_W + b
__global__ __launch_bounds__(256, 2) void setup_mm(Params p) {
  __shared__ u16 Al[2 * 128 * 64];
  __shared__ u16 Bl[2 * 64 * 64];
  int bid = blockIdx.x;
  if (bid < 128) {
    mm_body<MODE_G0>(Al, Bl, p.FRB, nullptr, 256, 1 << 30, 256, p.WT00,
                     (bid >> 6) * 128, bid & 63, 0, nullptr, p.G0B, nullptr,
                     p.G0P, nullptr, 0);
  } else if (bid < 224) {
    int b2 = bid - 128;
    mm_body<MODE_H>(Al, Bl, p.FRB, nullptr, 256, 1 << 30, 256, p.WIH,
                    (b2 / 48) * 128, b2 % 48, 0, nullptr, p.inh_b, nullptr,
                    p.HB, nullptr, 0);
  } else {
    int b2 = bid - 224;
    mm_body<MODE_C>(Al, Bl, p.FRB, nullptr, 256, 1 << 30, 256, p.WIC,
                    (b2 / 48) * 128, b2 % 48, 0, nullptr, p.inc_b, nullptr,
                    nullptr, p.CC, 0);
  }
}

// fp32 [K][N] sources -> bf16 transposed dst [Nout][Ktot] (K contiguous),
// optional gate permutation of output cols, zero pad k>=Kvalid / n>=Nvalid.
__global__ __launch_bounds__(256) void transpose_bf16(
    const float* __restrict__ srcA, const float* __restrict__ srcB,
    int srcStride, int kSplit, int Kvalid, int Nvalid, int perm,
    u16* __restrict__ dst, int Ktot) {
  __shared__ float tile[64][17];
  int P0 = blockIdx.x * 16;
  int k0 = blockIdx.y * 64;
  int t = threadIdx.x;
  int nl = t & 15;
  int kh = t >> 4;
  int P = P0 + nl;
  int n = perm ? permcol(P) : P;
  bool nok = (n < Nvalid);
#pragma unroll
  for (int q = 0; q < 4; ++q) {
    int kl = q * 16 + kh;
    int k = k0 + kl;
    float v = 0.f;
    if (nok && k < Kvalid) {
      const float* s = (k < kSplit) ? (srcA + (size_t)k * srcStride)
                                    : (srcB + (size_t)(k - kSplit) * srcStride);
      v = s[n];
    }
    tile[kl][nl] = v;
  }
  __syncthreads();
  int jo = t >> 4;
  int kb = (t & 15) << 2;
  u64 pk = (u64)f2bf(tile[kb + 0][jo]) | ((u64)f2bf(tile[kb + 1][jo]) << 16) |
           ((u64)f2bf(tile[kb + 2][jo]) << 32) |
           ((u64)f2bf(tile[kb + 3][jo]) << 48);
  *(u64*)(dst + (size_t)(P0 + jo) * Ktot + k0 + kb) = pk;
}

__global__ __launch_bounds__(256) void build_frame(const float* __restrict__ inputs,
                                                   u16* __restrict__ FRB) {
  int id = blockIdx.x * 256 + threadIdx.x;  // 256*256
  int b = id >> 8, k = id & 255;
  FRB[id] = (k < 204) ? f2bf(inputs[b * 204 + k]) : (u16)0;
}

// G0 bias incl. one-hot label row; layer1/2 combined biases (permuted cols)
__global__ __launch_bounds__(256) void build_bias(
    const float* __restrict__ W_ih0, const float* __restrict__ b_ih0,
    const float* __restrict__ b_hh0, const float* __restrict__ b_ih1,
    const float* __restrict__ b_hh1, const float* __restrict__ b_ih2,
    const float* __restrict__ b_hh2, const int* __restrict__ labels,
    float* __restrict__ G0B, float* __restrict__ B1P, float* __restrict__ B2P) {
  int P = blockIdx.x * 256 + threadIdx.x;  // 4096
  int n = permcol(P);
  int lab = labels[0];
  G0B[P] = W_ih0[(size_t)(204 + lab) * 4096 + n] + b_ih0[n] + b_hh0[n];
  B1P[P] = b_ih1[n] + b_hh1[n];
  B2P[P] = b_ih2[n] + b_hh2[n];
}

extern "C" void kernel_launch(void* const* d_in, const int* in_sizes, int n_in,
                              void* d_out, int out_size, void* d_ws,
                              size_t ws_size, hipStream_t stream) {
  const float* inputs = (const float*)d_in[0];
  const float* W_ih0 = (const float*)d_in[1];
  const float* W_hh0 = (const float*)d_in[2];
  const float* b_ih0 = (const float*)d_in[3];
  const float* b_hh0 = (const float*)d_in[4];
  const float* W_ih1 = (const float*)d_in[5];
  const float* W_hh1 = (const float*)d_in[6];
  const float* b_ih1 = (const float*)d_in[7];
  const float* b_hh1 = (const float*)d_in[8];
  const float* W_ih2 = (const float*)d_in[9];
  const float* W_hh2 = (const float*)d_in[10];
  const float* b_ih2 = (const float*)d_in[11];
  const float* b_hh2 = (const float*)d_in[12];
  const float* fc_W = (const float*)d_in[13];
  const float* fc_b = (const float*)d_in[14];
  const float* inh_W = (const float*)d_in[15];
  const float* inh_b = (const float*)d_in[16];
  const float* inc_W = (const float*)d_in[17];
  const float* inc_b = (const float*)d_in[18];
  const int* labels = (const int*)d_in[19];

  char* ws = (char*)d_ws;
  size_t off = 0;
  auto alloc = [&](size_t bytes) {
    void* r = ws + off;
    off = (off + bytes + 255) & ~(size_t)255;
    return r;
  };
  u16* WT0 = (u16*)alloc(4096ull * 1024 * 2);
  u16* WT1 = (u16*)alloc(4096ull * 2048 * 2);
  u16* WT2 = (u16*)alloc(4096ull * 2048 * 2);
  u16* WT00 = (u16*)alloc(4096ull * 256 * 2);
  u16* FCW = (u16*)alloc(256ull * 1024 * 2);
  u16* WIH = (u16*)alloc(3072ull * 256 * 2);
  u16* WIC = (u16*)alloc(3072ull * 256 * 2);
  u16* FRB = (u16*)alloc(256ull * 256 * 2);
  u16* HB = (u16*)alloc(3ull * 2 * 256 * 1024 * 2);
  u16* G0P = (u16*)alloc(256ull * 4096 * 2);
  float* G0B = (float*)alloc(4096ull * 4);
  float* B1P = (float*)alloc(4096ull * 4);
  float* B2P = (float*)alloc(4096ull * 4);
  float* CC = (float*)alloc(3ull * 256 * 1024 * 4);
  u32* BAR = (u32*)alloc(4096);  // 8 group counters (64-u32 apart) + flag @512
  if (off > ws_size) return;  // workspace too small: fail loudly (validation)

  const int BIG = 1 << 30;
  // weight repack (one-time per call)
  transpose_bf16<<<dim3(256, 16), 256, 0, stream>>>(W_hh0, nullptr, 4096, BIG, 1024, 4096, 1, WT0, 1024);
  transpose_bf16<<<dim3(256, 32), 256, 0, stream>>>(W_ih1, W_hh1, 4096, 1024, 2048, 4096, 1, WT1, 2048);
  transpose_bf16<<<dim3(256, 32), 256, 0, stream>>>(W_ih2, W_hh2, 4096, 1024, 2048, 4096, 1, WT2, 2048);
  transpose_bf16<<<dim3(256, 4), 256, 0, stream>>>(W_ih0, nullptr, 4096, BIG, 204, 4096, 1, WT00, 256);
  transpose_bf16<<<dim3(16, 16), 256, 0, stream>>>(fc_W, nullptr, 204, BIG, 1024, 204, 0, FCW, 1024);
  transpose_bf16<<<dim3(192, 4), 256, 0, stream>>>(inh_W, nullptr, 3072, BIG, 204, 3072, 0, WIH, 256);
  transpose_bf16<<<dim3(192, 4), 256, 0, stream>>>(inc_W, nullptr, 3072, BIG, 204, 3072, 0, WIC, 256);
  build_frame<<<256, 256, 0, stream>>>(inputs, FRB);
  build_bias<<<16, 256, 0, stream>>>(W_ih0, b_ih0, b_hh0, b_ih1, b_hh1, b_ih2,
                                     b_hh2, labels, G0B, B1P, B2P);
  hipMemsetAsync(BAR, 0, 4096, stream);

  Params p;
  p.fc_b = fc_b; p.inh_b = inh_b; p.inc_b = inc_b;
  p.WT0 = WT0; p.WT1 = WT1; p.WT2 = WT2; p.WT00 = WT00; p.FCW = FCW;
  p.WIH = WIH; p.WIC = WIC; p.FRB = FRB; p.HB = HB;
  p.G0P = G0P; p.G0B = G0B; p.B1P = B1P; p.B2P = B2P; p.CC = CC;
  p.out = (float*)d_out;

  setup_mm<<<320, 256, 0, stream>>>(p);

  // persistent pipelined sequence: one plain launch, software grid barrier
  persist_kernel<<<392, 256, 0, stream>>>(p, BAR);
}

// Round 13
// 5611.788 us; speedup vs baseline: 1.0898x; 1.0898x over previous
//
#include <hip/hip_runtime.h>

// DecoderRNN: 3-layer LSTM (H=1024) + fc, B=256, 128 steps, constant input.
// bf16 MFMA 16x16x32; gate-interleaved weight columns; persistent plain-launch
// kernel with software grid barrier.  Base = R8 structure (best: 40us/step).
// THIS ROUND: A-tiles (h-state) switch from MALL-coherent (sc0|sc1, no L2
// alloc -> 165MB/step redundant fabric reads) to L2-CACHED (sc0 only) loads;
// cross-XCD visibility via acquire fence (agent) after the barrier poll,
// pairing with the existing release fence. L2 now dedups the 8x per-XCD
// A-read redundancy: fabric bytes 246 -> ~82 MB/step. NT experiment reverted.

#define DEVINL static __device__ __forceinline__

typedef __bf16 bf16x8 __attribute__((ext_vector_type(8)));
typedef float f32x4 __attribute__((ext_vector_type(4)));
typedef unsigned short u16;
typedef unsigned int u32;
typedef unsigned long long u64;

DEVINL u16 f2bf(float f) {
  u32 u = __builtin_bit_cast(u32, f);
  u += 0x7fffu + ((u >> 16) & 1u);  // RNE
  return (u16)(u >> 16);
}
DEVINL float bf2f(u16 h) {
  u32 u = (u32)h << 16;
  return __builtin_bit_cast(float, u);
}
DEVINL float sigm(float x) { return 1.0f / (1.0f + __expf(-x)); }
DEVINL float tanhfast(float x) { return 1.0f - 2.0f / (1.0f + __expf(2.0f * x)); }

// L1-bypass, L2-CACHED global->LDS (h-state: fresh after acquire-fence inv;
// L2 dedups the 8x per-XCD redundancy)
DEVINL void glds_a(const u16* g, u16* l) {
  __builtin_amdgcn_global_load_lds(
      (const __attribute__((address_space(1))) u32*)g,
      (__attribute__((address_space(3))) u32*)l, 16, 0, 1);  // sc0
}
// fully cached global->LDS (weights: read-only)
DEVINL void glds_w(const u16* g, u16* l) {
  __builtin_amdgcn_global_load_lds(
      (const __attribute__((address_space(1))) u32*)g,
      (__attribute__((address_space(3))) u32*)l, 16, 0, 0);
}

// permuted column index -> original gate column: P = grp*64 + g*16 + jj
DEVINL int permcol(int P) {
  int grp = P >> 6, g = (P >> 4) & 3, jj = P & 15;
  return g * 1024 + grp * 16 + jj;
}

struct Params {
  const float* fc_b;
  const float* inh_b;
  const float* inc_b;
  const u16 *WT0, *WT1, *WT2, *WT00, *FCW, *WIH, *WIC, *FRB;
  u16* HB;   // h state bf16: [layer][parity][256][1024]  (1<<18 u16 per buf)
  u16* G0P;  // precomputed layer0 input gates, bf16 [256][4096]
  float *G0B, *B1P, *B2P, *CC;  // CC: c state fp32 [layer][256][1024]
  float* out;
};

#define MODE_L0 0
#define MODE_L 1
#define MODE_FC 2
#define MODE_G0 3
#define MODE_H 4
#define MODE_C 5

// one 64-K tile: per thread 4 A-loads (sc0, L2-cached) + 2 B-loads (cached),
// direct to LDS. Source-side XOR swizzle (granule ^ row&7); LDS dest linear.
DEVINL void issue_tile(int kt, const u16* A0, const u16* A1, int kSplit, int sA,
                       int K, const u16* Wt, int m0, int wrow,
                       const int (&rq)[4], const int (&kqs)[4],
                       const int (&lo)[4], u16* Abuf, u16* Bbuf) {
  const u16* Ab = (kt < kSplit) ? (A0 + kt) : (A1 + (kt - kSplit));
#pragma unroll
  for (int q = 0; q < 4; ++q)
    glds_a(Ab + (size_t)(m0 + rq[q]) * sA + kqs[q] * 8, Abuf + lo[q]);
  const u16* Bb = Wt + kt;
#pragma unroll
  for (int q = 0; q < 2; ++q)
    glds_w(Bb + (size_t)(wrow + rq[q]) * K + kqs[q] * 8, Bbuf + lo[q]);
}

DEVINL void mfma_tile(const u16* Al, const u16* Bl, f32x4 (&acc)[2][4], int rl0,
                      int hh, int e7, int jj) {
#pragma unroll
  for (int kk = 0; kk < 2; ++kk) {
    int sl = (((kk << 2) | hh) ^ e7) * 8;
    bf16x8 a0 = *(const bf16x8*)(Al + rl0 * 64 + sl);
    bf16x8 a1 = *(const bf16x8*)(Al + (rl0 + 16) * 64 + sl);
    bf16x8 b0 = *(const bf16x8*)(Bl + (jj)*64 + sl);
    bf16x8 b1 = *(const bf16x8*)(Bl + (16 + jj) * 64 + sl);
    bf16x8 b2 = *(const bf16x8*)(Bl + (32 + jj) * 64 + sl);
    bf16x8 b3 = *(const bf16x8*)(Bl + (48 + jj) * 64 + sl);
    acc[0][0] = __builtin_amdgcn_mfma_f32_16x16x32_bf16(a0, b0, acc[0][0], 0, 0, 0);
    acc[0][1] = __builtin_amdgcn_mfma_f32_16x16x32_bf16(a0, b1, acc[0][1], 0, 0, 0);
    acc[0][2] = __builtin_amdgcn_mfma_f32_16x16x32_bf16(a0, b2, acc[0][2], 0, 0, 0);
    acc[0][3] = __builtin_amdgcn_mfma_f32_16x16x32_bf16(a0, b3, acc[0][3], 0, 0, 0);
    acc[1][0] = __builtin_amdgcn_mfma_f32_16x16x32_bf16(a1, b0, acc[1][0], 0, 0, 0);
    acc[1][1] = __builtin_amdgcn_mfma_f32_16x16x32_bf16(a1, b1, acc[1][1], 0, 0, 0);
    acc[1][2] = __builtin_amdgcn_mfma_f32_16x16x32_bf16(a1, b2, acc[1][2], 0, 0, 0);
    acc[1][3] = __builtin_amdgcn_mfma_f32_16x16x32_bf16(a1, b3, acc[1][3], 0, 0, 0);
  }
}

// Block: 256 threads = 4 waves, output tile 128(M) x 64(N); wave w = rows
// [w*32, w*32+32): 2 M-frags x 4 N-frags. LDS double-buffered.
// Counted vmcnt(6): next tile's 6 loads stay in flight across both barriers.
template <int MODE>
DEVINL void mm_body(u16* Al, u16* Bl, const u16* A0, const u16* A1, int sA,
                    int kSplit, int K, const u16* Wt, int m0, int bn, int t,
                    const u16* Gfull, const float* biasP, float* Cst, u16* Hout,
                    float* outp) {
  const int tid = threadIdx.x;
  const int l = tid & 63;
  const int w = tid >> 6;
  const int hh = (l >> 4) & 3;
  const int jj = l & 15;
  const int rl0 = w * 32 + jj;
  const int e7 = l & 7;

  int rq[4], kqs[4], lo[4];
#pragma unroll
  for (int q = 0; q < 4; ++q) {
    int L = tid + q * 256;
    rq[q] = L >> 3;
    kqs[q] = (L & 7) ^ (rq[q] & 7);       // source-swizzled granule
    lo[q] = ((tid & ~63) + q * 256) * 8;  // wave-uniform LDS base (u16 units)
  }

  f32x4 acc[2][4];
#pragma unroll
  for (int m = 0; m < 2; ++m)
#pragma unroll
    for (int g = 0; g < 4; ++g) acc[m][g] = (f32x4){0.f, 0.f, 0.f, 0.f};

  const int wrow = bn * 64;
  const int n = K >> 6;  // 64-K tiles

  issue_tile(0, A0, A1, kSplit, sA, K, Wt, m0, wrow, rq, kqs, lo, Al, Bl);
  issue_tile(64, A0, A1, kSplit, sA, K, Wt, m0, wrow, rq, kqs, lo, Al + 8192,
             Bl + 4096);

  for (int j = 0; j < n; ++j) {
    u16* Ac = Al + (j & 1) * 8192;
    u16* Bc = Bl + (j & 1) * 4096;
    if (j < n - 1)
      asm volatile("s_waitcnt vmcnt(6)" ::: "memory");
    else
      asm volatile("s_waitcnt vmcnt(0)" ::: "memory");
    __builtin_amdgcn_s_barrier();
    __builtin_amdgcn_sched_barrier(0);
    mfma_tile(Ac, Bc, acc, rl0, hh, e7, jj);
    __builtin_amdgcn_sched_barrier(0);
    __builtin_amdgcn_s_barrier();
    if (j + 2 < n)
      issue_tile((j + 2) * 64, A0, A1, kSplit, sA, K, Wt, m0, wrow, rq, kqs, lo,
                 Ac, Bc);
  }

  // C/D layout: col = lane&15, row = (lane>>4)*4 + reg  [m89-verified]
  const int rb = m0 + w * 32 + (hh << 2);
  if (MODE <= MODE_L) {
    float add0 = 0.f, add1 = 0.f, add2 = 0.f, add3 = 0.f;
    if (MODE == MODE_L) {
      add0 = biasP[bn * 64 + jj];
      add1 = biasP[bn * 64 + 16 + jj];
      add2 = biasP[bn * 64 + 32 + jj];
      add3 = biasP[bn * 64 + 48 + jj];
    }
    const int j = bn * 16 + jj;  // hidden unit
#pragma unroll
    for (int m = 0; m < 2; ++m) {
#pragma unroll
      for (int r = 0; r < 4; ++r) {
        int b = rb + m * 16 + r;
        float g0v, g1v, g2v, g3v;
        if (MODE == MODE_L0) {
          const u16* G = Gfull + (size_t)b * 4096 + bn * 64 + jj;
          g0v = acc[m][0][r] + bf2f(G[0]);
          g1v = acc[m][1][r] + bf2f(G[16]);
          g2v = acc[m][2][r] + bf2f(G[32]);
          g3v = acc[m][3][r] + bf2f(G[48]);
        } else {
          g0v = acc[m][0][r] + add0;
          g1v = acc[m][1][r] + add1;
          g2v = acc[m][2][r] + add2;
          g3v = acc[m][3][r] + add3;
        }
        float iv = sigm(g0v), fv = sigm(g1v), gv = tanhfast(g2v), ov = sigm(g3v);
        size_t ci = (size_t)b * 1024 + j;
        float cn = fv * Cst[ci] + iv * gv;
        Cst[ci] = cn;
        Hout[ci] = f2bf(ov * tanhfast(cn));
      }
    }
  } else if (MODE == MODE_FC) {
#pragma unroll
    for (int g = 0; g < 4; ++g) {
      int nn = bn * 64 + g * 16 + jj;
      if (nn < 204) {
        float bv2 = biasP[nn];
#pragma unroll
        for (int m = 0; m < 2; ++m)
#pragma unroll
          for (int r = 0; r < 4; ++r) {
            int b = rb + m * 16 + r;
            outp[((size_t)b * 128 + t) * 204 + nn] = acc[m][g][r] + bv2;
          }
      }
    }
  } else if (MODE == MODE_G0) {
#pragma unroll
    for (int g = 0; g < 4; ++g) {
      int P = bn * 64 + g * 16 + jj;
      float bv2 = biasP[P];
#pragma unroll
      for (int m = 0; m < 2; ++m)
#pragma unroll
        for (int r = 0; r < 4; ++r) {
          int b = rb + m * 16 + r;
          Hout[(size_t)b * 4096 + P] = f2bf(acc[m][g][r] + bv2);
        }
    }
  } else {  // MODE_H / MODE_C : init states, cols are orig n = lay*1024 + j
#pragma unroll
    for (int g = 0; g < 4; ++g) {
      int nn = bn * 64 + g * 16 + jj;
      int lay = nn >> 10, j2 = nn & 1023;
      float bv2 = biasP[nn];
#pragma unroll
      for (int m = 0; m < 2; ++m)
#pragma unroll
        for (int r = 0; r < 4; ++r) {
          int b = rb + m * 16 + r;
          float v = acc[m][g][r] + bv2;
          if (MODE == MODE_H)
            Hout[(size_t)((lay * 2 + 1) * 256 + b) * 1024 + j2] = f2bf(v);
          else
            outp[(size_t)(lay * 256 + b) * 1024 + j2] = v;
        }
    }
  }
}

// Grid barrier: release fence (wb dirty h/c lines to MALL) before arrive;
// ACQUIRE fence (inv stale L2/L1) after the poll, before next step's loads.
// Two-level counter/flag, groups of 49 (R8-proven shape).
DEVINL void grid_barrier(u32* bar, int bid, int ep) {
  __syncthreads();
  if (threadIdx.x == 0) {
    __builtin_amdgcn_fence(__ATOMIC_RELEASE, "agent");  // wb dirty lines
    __hip_atomic_fetch_add(bar + (bid & 7) * 64, 1u, __ATOMIC_RELAXED,
                           __HIP_MEMORY_SCOPE_AGENT);
    if (bid == 0) {
#pragma unroll 1
      for (int g = 0; g < 8; ++g)
        while (__hip_atomic_load(bar + g * 64, __ATOMIC_RELAXED,
                                 __HIP_MEMORY_SCOPE_AGENT) < (u32)ep * 49u)
          __builtin_amdgcn_s_sleep(8);
      __hip_atomic_store(bar + 512, (u32)ep, __ATOMIC_RELAXED,
                         __HIP_MEMORY_SCOPE_AGENT);
    } else {
#pragma unroll 1
      while (__hip_atomic_load(bar + 512, __ATOMIC_RELAXED,
                               __HIP_MEMORY_SCOPE_AGENT) < (u32)ep)
        __builtin_amdgcn_s_sleep(8);
    }
    __builtin_amdgcn_fence(__ATOMIC_ACQUIRE, "agent");  // inv stale caches
  }
  __syncthreads();
}

// Persistent pipelined kernel, PLAIN launch; 392 blocks co-resident:
// LDS 48KB -> 3 blocks/CU; launch_bounds(256,2) -> VGPR<=128 -> >=2/CU;
// 392 <= 512. bid&7 ~ XCD affinity (bn>>3 == bid&7) and barrier group (49).
__global__ __launch_bounds__(256, 2) void persist_kernel(Params p, u32* bar) {
  __shared__ u16 Al[2 * 128 * 64];  // 32KB
  __shared__ u16 Bl[2 * 64 * 64];   // 16KB
  const int bid = blockIdx.x;
  int job, mb, bn;
  if (bid < 384) {
    job = bid >> 7;
    int r = bid & 127;
    bn = (r & 7) * 8 + (r >> 4);  // bn>>3 == bid&7 (XCD-affine weight slice)
    mb = (r >> 3) & 1;
  } else {
    job = 3;
    int r = bid - 384;
    mb = r >> 2;
    bn = r & 3;
  }
  u16* HB = p.HB;
#define HBP(lay, pp) (HB + (size_t)(((lay)*2 + (pp)) << 18))
  for (int i = 0; i <= 130; ++i) {
    int t = i - job;
    if ((unsigned)t < 128u) {
      int par = t & 1, pv = par ^ 1;
      if (job == 0) {
        mm_body<MODE_L0>(Al, Bl, HBP(0, pv), nullptr, 1024, 1 << 30, 1024,
                         p.WT0, mb * 128, bn, t, p.G0P, nullptr, p.CC,
                         HBP(0, par), nullptr);
      } else if (job == 1) {
        mm_body<MODE_L>(Al, Bl, HBP(0, par), HBP(1, pv), 1024, 1024, 2048,
                        p.WT1, mb * 128, bn, t, nullptr, p.B1P,
                        p.CC + (size_t)256 * 1024, HBP(1, par), nullptr);
      } else if (job == 2) {
        mm_body<MODE_L>(Al, Bl, HBP(1, par), HBP(2, pv), 1024, 1024, 2048,
                        p.WT2, mb * 128, bn, t, nullptr, p.B2P,
                        p.CC + (size_t)512 * 1024, HBP(2, par), nullptr);
      } else {
        mm_body<MODE_FC>(Al, Bl, HBP(2, par), nullptr, 1024, 1 << 30, 1024,
                         p.FCW, mb * 128, bn, t, nullptr, p.fc_b, nullptr,
                         nullptr, p.out);
      }
    }
    if (i < 130) grid_barrier(bar, bid, i + 1);
  }
#undef HBP
}

// one-time: G0 = x_in@W_ih0+biases (permuted), h/c init = frame@in{h,c}_W + b
__global__ __launch_bounds__(256, 2) void setup_mm(Params p) {
  __shared__ u16 Al[2 * 128 * 64];
  __shared__ u16 Bl[2 * 64 * 64];
  int bid = blockIdx.x;
  if (bid < 128) {
    mm_body<MODE_G0>(Al, Bl, p.FRB, nullptr, 256, 1 << 30, 256, p.WT00,
                     (bid >> 6) * 128, bid & 63, 0, nullptr, p.G0B, nullptr,
                     p.G0P, nullptr);
  } else if (bid < 224) {
    int b2 = bid - 128;
    mm_body<MODE_H>(Al, Bl, p.FRB, nullptr, 256, 1 << 30, 256, p.WIH,
                    (b2 / 48) * 128, b2 % 48, 0, nullptr, p.inh_b, nullptr,
                    p.HB, nullptr);
  } else {
    int b2 = bid - 224;
    mm_body<MODE_C>(Al, Bl, p.FRB, nullptr, 256, 1 << 30, 256, p.WIC,
                    (b2 / 48) * 128, b2 % 48, 0, nullptr, p.inc_b, nullptr,
                    nullptr, p.CC);
  }
}

// fp32 [K][N] sources -> bf16 transposed dst [Nout][Ktot] (K contiguous),
// optional gate permutation of output cols, zero pad k>=Kvalid / n>=Nvalid.
__global__ __launch_bounds__(256) void transpose_bf16(
    const float* __restrict__ srcA, const float* __restrict__ srcB,
    int srcStride, int kSplit, int Kvalid, int Nvalid, int perm,
    u16* __restrict__ dst, int Ktot) {
  __shared__ float tile[64][17];
  int P0 = blockIdx.x * 16;
  int k0 = blockIdx.y * 64;
  int t = threadIdx.x;
  int nl = t & 15;
  int kh = t >> 4;
  int P = P0 + nl;
  int n = perm ? permcol(P) : P;
  bool nok = (n < Nvalid);
#pragma unroll
  for (int q = 0; q < 4; ++q) {
    int kl = q * 16 + kh;
    int k = k0 + kl;
    float v = 0.f;
    if (nok && k < Kvalid) {
      const float* s = (k < kSplit) ? (srcA + (size_t)k * srcStride)
                                    : (srcB + (size_t)(k - kSplit) * srcStride);
      v = s[n];
    }
    tile[kl][nl] = v;
  }
  __syncthreads();
  int jo = t >> 4;
  int kb = (t & 15) << 2;
  u64 pk = (u64)f2bf(tile[kb + 0][jo]) | ((u64)f2bf(tile[kb + 1][jo]) << 16) |
           ((u64)f2bf(tile[kb + 2][jo]) << 32) |
           ((u64)f2bf(tile[kb + 3][jo]) << 48);
  *(u64*)(dst + (size_t)(P0 + jo) * Ktot + k0 + kb) = pk;
}

__global__ __launch_bounds__(256) void build_frame(const float* __restrict__ inputs,
                                                   u16* __restrict__ FRB) {
  int id = blockIdx.x * 256 + threadIdx.x;  // 256*256
  int b = id >> 8, k = id & 255;
  FRB[id] = (k < 204) ? f2bf(inputs[b * 204 + k]) : (u16)0;
}

// G0 bias incl. one-hot label row; layer1/2 combined biases (permuted cols)
__global__ __launch_bounds__(256) void build_bias(
    const float* __restrict__ W_ih0, const float* __restrict__ b_ih0,
    const float* __restrict__ b_hh0, const float* __restrict__ b_ih1,
    const float* __restrict__ b_hh1, const float* __restrict__ b_ih2,
    const float* __restrict__ b_hh2, const int* __restrict__ labels,
    float* __restrict__ G0B, float* __restrict__ B1P, float* __restrict__ B2P) {
  int P = blockIdx.x * 256 + threadIdx.x;  // 4096
  int n = permcol(P);
  int lab = labels[0];
  G0B[P] = W_ih0[(size_t)(204 + lab) * 4096 + n] + b_ih0[n] + b_hh0[n];
  B1P[P] = b_ih1[n] + b_hh1[n];
  B2P[P] = b_ih2[n] + b_hh2[n];
}

extern "C" void kernel_launch(void* const* d_in, const int* in_sizes, int n_in,
                              void* d_out, int out_size, void* d_ws,
                              size_t ws_size, hipStream_t stream) {
  const float* inputs = (const float*)d_in[0];
  const float* W_ih0 = (const float*)d_in[1];
  const float* W_hh0 = (const float*)d_in[2];
  const float* b_ih0 = (const float*)d_in[3];
  const float* b_hh0 = (const float*)d_in[4];
  const float* W_ih1 = (const float*)d_in[5];
  const float* W_hh1 = (const float*)d_in[6];
  const float* b_ih1 = (const float*)d_in[7];
  const float* b_hh1 = (const float*)d_in[8];
  const float* W_ih2 = (const float*)d_in[9];
  const float* W_hh2 = (const float*)d_in[10];
  const float* b_ih2 = (const float*)d_in[11];
  const float* b_hh2 = (const float*)d_in[12];
  const float* fc_W = (const float*)d_in[13];
  const float* fc_b = (const float*)d_in[14];
  const float* inh_W = (const float*)d_in[15];
  const float* inh_b = (const float*)d_in[16];
  const float* inc_W = (const float*)d_in[17];
  const float* inc_b = (const float*)d_in[18];
  const int* labels = (const int*)d_in[19];

  char* ws = (char*)d_ws;
  size_t off = 0;
  auto alloc = [&](size_t bytes) {
    void* r = ws + off;
    off = (off + bytes + 255) & ~(size_t)255;
    return r;
  };
  u16* WT0 = (u16*)alloc(4096ull * 1024 * 2);
  u16* WT1 = (u16*)alloc(4096ull * 2048 * 2);
  u16* WT2 = (u16*)alloc(4096ull * 2048 * 2);
  u16* WT00 = (u16*)alloc(4096ull * 256 * 2);
  u16* FCW = (u16*)alloc(256ull * 1024 * 2);
  u16* WIH = (u16*)alloc(3072ull * 256 * 2);
  u16* WIC = (u16*)alloc(3072ull * 256 * 2);
  u16* FRB = (u16*)alloc(256ull * 256 * 2);
  u16* HB = (u16*)alloc(3ull * 2 * 256 * 1024 * 2);
  u16* G0P = (u16*)alloc(256ull * 4096 * 2);
  float* G0B = (float*)alloc(4096ull * 4);
  float* B1P = (float*)alloc(4096ull * 4);
  float* B2P = (float*)alloc(4096ull * 4);
  float* CC = (float*)alloc(3ull * 256 * 1024 * 4);
  u32* BAR = (u32*)alloc(4096);  // 8 group counters (64-u32 apart) + flag @512
  if (off > ws_size) return;  // workspace too small: fail loudly (validation)

  const int BIG = 1 << 30;
  // weight repack (one-time per call)
  transpose_bf16<<<dim3(256, 16), 256, 0, stream>>>(W_hh0, nullptr, 4096, BIG, 1024, 4096, 1, WT0, 1024);
  transpose_bf16<<<dim3(256, 32), 256, 0, stream>>>(W_ih1, W_hh1, 4096, 1024, 2048, 4096, 1, WT1, 2048);
  transpose_bf16<<<dim3(256, 32), 256, 0, stream>>>(W_ih2, W_hh2, 4096, 1024, 2048, 4096, 1, WT2, 2048);
  transpose_bf16<<<dim3(256, 4), 256, 0, stream>>>(W_ih0, nullptr, 4096, BIG, 204, 4096, 1, WT00, 256);
  transpose_bf16<<<dim3(16, 16), 256, 0, stream>>>(fc_W, nullptr, 204, BIG, 1024, 204, 0, FCW, 1024);
  transpose_bf16<<<dim3(192, 4), 256, 0, stream>>>(inh_W, nullptr, 3072, BIG, 204, 3072, 0, WIH, 256);
  transpose_bf16<<<dim3(192, 4), 256, 0, stream>>>(inc_W, nullptr, 3072, BIG, 204, 3072, 0, WIC, 256);
  build_frame<<<256, 256, 0, stream>>>(inputs, FRB);
  build_bias<<<16, 256, 0, stream>>>(W_ih0, b_ih0, b_hh0, b_ih1, b_hh1, b_ih2,
                                     b_hh2, labels, G0B, B1P, B2P);
  hipMemsetAsync(BAR, 0, 4096, stream);

  Params p;
  p.fc_b = fc_b; p.inh_b = inh_b; p.inc_b = inc_b;
  p.WT0 = WT0; p.WT1 = WT1; p.WT2 = WT2; p.WT00 = WT00; p.FCW = FCW;
  p.WIH = WIH; p.WIC = WIC; p.FRB = FRB; p.HB = HB;
  p.G0P = G0P; p.G0B = G0B; p.B1P = B1P; p.B2P = B2P; p.CC = CC;
  p.out = (float*)d_out;

  setup_mm<<<320, 256, 0, stream>>>(p);

  // persistent pipelined sequence: one plain launch, software grid barrier
  persist_kernel<<<392, 256, 0, stream>>>(p, BAR);
}

// Round 14
// 5484.063 us; speedup vs baseline: 1.1152x; 1.0233x over previous
//
#include <hip/hip_runtime.h>

// DecoderRNN: 3-layer LSTM (H=1024) + fc, B=256, 128 steps, constant input.
// bf16 MFMA 16x16x32; gate-interleaved weight columns; persistent plain-launch
// kernel with software grid barrier (release-only fence; h-state via
// device-coherent loads — the R8-proven correctness pattern).
// THIS ROUND: block tile 128(M) x 128(N) (2 gate groups) -> 64 blocks/job,
// A(h) fabric traffic halves: 248 -> 131 MB/step. Grid 196 <= 256 CUs
// (1 block/CU, 96KB LDS, depth-3 pipeline, counted vmcnt(8)).
// R13's acquire-fence reverted (null); R12's NT reverted (negative).

#define DEVINL static __device__ __forceinline__

typedef __bf16 bf16x8 __attribute__((ext_vector_type(8)));
typedef float f32x4 __attribute__((ext_vector_type(4)));
typedef unsigned short u16;
typedef unsigned int u32;
typedef unsigned long long u64;

DEVINL u16 f2bf(float f) {
  u32 u = __builtin_bit_cast(u32, f);
  u += 0x7fffu + ((u >> 16) & 1u);  // RNE
  return (u16)(u >> 16);
}
DEVINL float bf2f(u16 h) {
  u32 u = (u32)h << 16;
  return __builtin_bit_cast(float, u);
}
DEVINL float sigm(float x) { return 1.0f / (1.0f + __expf(-x)); }
DEVINL float tanhfast(float x) { return 1.0f - 2.0f / (1.0f + __expf(2.0f * x)); }

// device-coherent global->LDS (h-state: written by other XCDs) [R8-proven]
DEVINL void glds_coh(const u16* g, u16* l) {
  __builtin_amdgcn_global_load_lds(
      (const __attribute__((address_space(1))) u32*)g,
      (__attribute__((address_space(3))) u32*)l, 16, 0, 17);  // sc0|sc1
}
// cached global->LDS (weights: read-only)
DEVINL void glds_w(const u16* g, u16* l) {
  __builtin_amdgcn_global_load_lds(
      (const __attribute__((address_space(1))) u32*)g,
      (__attribute__((address_space(3))) u32*)l, 16, 0, 0);
}

// permuted column index -> original gate column: P = grp*64 + g*16 + jj
DEVINL int permcol(int P) {
  int grp = P >> 6, g = (P >> 4) & 3, jj = P & 15;
  return g * 1024 + grp * 16 + jj;
}

struct Params {
  const float* fc_b;
  const float* inh_b;
  const float* inc_b;
  const u16 *WT0, *WT1, *WT2, *WT00, *FCW, *WIH, *WIC, *FRB;
  u16* HB;   // h state bf16: [layer][parity][256][1024]  (1<<18 u16 per buf)
  u16* G0P;  // precomputed layer0 input gates, bf16 [256][4096]
  float *G0B, *B1P, *B2P, *CC;  // CC: c state fp32 [layer][256][1024]
  float* out;
};

#define MODE_L0 0
#define MODE_L 1
#define MODE_FC 2
#define MODE_G0 3
#define MODE_H 4
#define MODE_C 5

#define SLOT 8192  // u16 per slot per operand (128 rows x 64 k)

// one 64-K tile: per thread 2 A-loads (coherent) + 2 B-loads (cached),
// direct to LDS. Source-side XOR swizzle (granule ^ row&7); LDS dest linear.
DEVINL void issue_tile(int kt, const u16* A0, const u16* A1, int kSplit, int sA,
                       int K, const u16* Wt, int m0, int wrow,
                       const int (&rq)[2], const int (&kqs)[2],
                       const int (&lo)[2], u16* Abuf, u16* Bbuf) {
  const u16* Ab = (kt < kSplit) ? (A0 + kt) : (A1 + (kt - kSplit));
#pragma unroll
  for (int q = 0; q < 2; ++q)
    glds_coh(Ab + (size_t)(m0 + rq[q]) * sA + kqs[q] * 8, Abuf + lo[q]);
  const u16* Bb = Wt + kt;
#pragma unroll
  for (int q = 0; q < 2; ++q)
    glds_w(Bb + (size_t)(wrow + rq[q]) * K + kqs[q] * 8, Bbuf + lo[q]);
}

// wave computes 32(M) x 64(N): 2 M-frags x 4 N-frags, K=64 per tile
DEVINL void mfma_tile(const u16* Al, const u16* Bl, f32x4 (&acc)[2][4], int rl0,
                      int nb0, int hh, int e7) {
#pragma unroll
  for (int kk = 0; kk < 2; ++kk) {
    int sl = (((kk << 2) | hh) ^ e7) * 8;
    bf16x8 a0 = *(const bf16x8*)(Al + rl0 * 64 + sl);
    bf16x8 a1 = *(const bf16x8*)(Al + (rl0 + 16) * 64 + sl);
    bf16x8 b0 = *(const bf16x8*)(Bl + (nb0)*64 + sl);
    bf16x8 b1 = *(const bf16x8*)(Bl + (nb0 + 16) * 64 + sl);
    bf16x8 b2 = *(const bf16x8*)(Bl + (nb0 + 32) * 64 + sl);
    bf16x8 b3 = *(const bf16x8*)(Bl + (nb0 + 48) * 64 + sl);
    acc[0][0] = __builtin_amdgcn_mfma_f32_16x16x32_bf16(a0, b0, acc[0][0], 0, 0, 0);
    acc[0][1] = __builtin_amdgcn_mfma_f32_16x16x32_bf16(a0, b1, acc[0][1], 0, 0, 0);
    acc[0][2] = __builtin_amdgcn_mfma_f32_16x16x32_bf16(a0, b2, acc[0][2], 0, 0, 0);
    acc[0][3] = __builtin_amdgcn_mfma_f32_16x16x32_bf16(a0, b3, acc[0][3], 0, 0, 0);
    acc[1][0] = __builtin_amdgcn_mfma_f32_16x16x32_bf16(a1, b0, acc[1][0], 0, 0, 0);
    acc[1][1] = __builtin_amdgcn_mfma_f32_16x16x32_bf16(a1, b1, acc[1][1], 0, 0, 0);
    acc[1][2] = __builtin_amdgcn_mfma_f32_16x16x32_bf16(a1, b2, acc[1][2], 0, 0, 0);
    acc[1][3] = __builtin_amdgcn_mfma_f32_16x16x32_bf16(a1, b3, acc[1][3], 0, 0, 0);
  }
}

// Block: 512 threads = 8 waves (4M x 2N), output tile 128(M) x 128(N).
// Wave w: rows m0 + (w&3)*32 + [0,32), permuted cols bn*128 + (w>>2)*64 +
// [0,64) (one full gate group per wave -> lane-local cell update).
// LDS triple-buffered (depth-3); counted vmcnt: 2 tiles (8 loads) in flight.
template <int MODE>
DEVINL void mm_body(u16* Al, u16* Bl, const u16* A0, const u16* A1, int sA,
                    int kSplit, int K, const u16* Wt, int m0, int bn, int t,
                    const u16* Gfull, const float* biasP, float* Cst, u16* Hout,
                    float* outp) {
  const int tid = threadIdx.x;
  const int l = tid & 63;
  const int w = tid >> 6;  // 0..7
  const int hh = (l >> 4) & 3;
  const int jj = l & 15;
  const int rl0 = (w & 3) * 32 + jj;   // A row of m-frag 0 (rl0&7 == l&7)
  const int nb0 = (w >> 2) * 64 + jj;  // B-tile row of n-frag 0
  const int e7 = l & 7;

  int rq[2], kqs[2], lo[2];
#pragma unroll
  for (int q = 0; q < 2; ++q) {
    int L = tid + q * 512;
    rq[q] = L >> 3;                       // 0..127
    kqs[q] = (L & 7) ^ (rq[q] & 7);       // source-swizzled granule
    lo[q] = ((tid & ~63) + q * 512) * 8;  // wave-uniform LDS base (u16)
  }

  f32x4 acc[2][4];
#pragma unroll
  for (int m = 0; m < 2; ++m)
#pragma unroll
    for (int g = 0; g < 4; ++g) acc[m][g] = (f32x4){0.f, 0.f, 0.f, 0.f};

  const int wrow = bn * 128;
  const int nt = K >> 6;  // 64-K tiles; nt in {4,16,32}

  issue_tile(0, A0, A1, kSplit, sA, K, Wt, m0, wrow, rq, kqs, lo, Al, Bl);
  issue_tile(64, A0, A1, kSplit, sA, K, Wt, m0, wrow, rq, kqs, lo, Al + SLOT,
             Bl + SLOT);
  issue_tile(128, A0, A1, kSplit, sA, K, Wt, m0, wrow, rq, kqs, lo,
             Al + 2 * SLOT, Bl + 2 * SLOT);

  for (int j = 0; j < nt; ++j) {
    int s = j % 3;
    u16* Ac = Al + s * SLOT;
    u16* Bc = Bl + s * SLOT;
    if (j < nt - 2)
      asm volatile("s_waitcnt vmcnt(8)" ::: "memory");
    else if (j == nt - 2)
      asm volatile("s_waitcnt vmcnt(4)" ::: "memory");
    else
      asm volatile("s_waitcnt vmcnt(0)" ::: "memory");
    __builtin_amdgcn_s_barrier();
    __builtin_amdgcn_sched_barrier(0);
    mfma_tile(Ac, Bc, acc, rl0, nb0, hh, e7);
    __builtin_amdgcn_sched_barrier(0);
    __builtin_amdgcn_s_barrier();
    if (j + 3 < nt)
      issue_tile((j + 3) * 64, A0, A1, kSplit, sA, K, Wt, m0, wrow, rq, kqs, lo,
                 Ac, Bc);
  }

  // C/D layout: col = lane&15, row = (lane>>4)*4 + reg  [m89-verified]
  const int rb = m0 + (w & 3) * 32 + (hh << 2);
  const int nb = bn * 128 + (w >> 2) * 64;  // permuted col base (gate group)
  if (MODE <= MODE_L) {
    float add0 = 0.f, add1 = 0.f, add2 = 0.f, add3 = 0.f;
    if (MODE == MODE_L) {
      add0 = biasP[nb + jj];
      add1 = biasP[nb + 16 + jj];
      add2 = biasP[nb + 32 + jj];
      add3 = biasP[nb + 48 + jj];
    }
    const int j = (nb >> 6) * 16 + jj;  // hidden unit
#pragma unroll
    for (int m = 0; m < 2; ++m) {
#pragma unroll
      for (int r = 0; r < 4; ++r) {
        int b = rb + m * 16 + r;
        float g0v, g1v, g2v, g3v;
        if (MODE == MODE_L0) {
          const u16* G = Gfull + (size_t)b * 4096 + nb + jj;
          g0v = acc[m][0][r] + bf2f(G[0]);
          g1v = acc[m][1][r] + bf2f(G[16]);
          g2v = acc[m][2][r] + bf2f(G[32]);
          g3v = acc[m][3][r] + bf2f(G[48]);
        } else {
          g0v = acc[m][0][r] + add0;
          g1v = acc[m][1][r] + add1;
          g2v = acc[m][2][r] + add2;
          g3v = acc[m][3][r] + add3;
        }
        float iv = sigm(g0v), fv = sigm(g1v), gv = tanhfast(g2v), ov = sigm(g3v);
        size_t ci = (size_t)b * 1024 + j;
        float cn = fv * Cst[ci] + iv * gv;
        Cst[ci] = cn;
        Hout[ci] = f2bf(ov * tanhfast(cn));
      }
    }
  } else if (MODE == MODE_FC) {
#pragma unroll
    for (int g = 0; g < 4; ++g) {
      int nn = nb + g * 16 + jj;
      if (nn < 204) {
        float bv2 = biasP[nn];
#pragma unroll
        for (int m = 0; m < 2; ++m)
#pragma unroll
          for (int r = 0; r < 4; ++r) {
            int b = rb + m * 16 + r;
            outp[((size_t)b * 128 + t) * 204 + nn] = acc[m][g][r] + bv2;
          }
      }
    }
  } else if (MODE == MODE_G0) {
#pragma unroll
    for (int g = 0; g < 4; ++g) {
      int P = nb + g * 16 + jj;
      float bv2 = biasP[P];
#pragma unroll
      for (int m = 0; m < 2; ++m)
#pragma unroll
        for (int r = 0; r < 4; ++r) {
          int b = rb + m * 16 + r;
          Hout[(size_t)b * 4096 + P] = f2bf(acc[m][g][r] + bv2);
        }
    }
  } else {  // MODE_H / MODE_C : init states, cols are orig n = lay*1024 + j
#pragma unroll
    for (int g = 0; g < 4; ++g) {
      int nn = nb + g * 16 + jj;
      int lay = nn >> 10, j2 = nn & 1023;
      float bv2 = biasP[nn];
#pragma unroll
      for (int m = 0; m < 2; ++m)
#pragma unroll
        for (int r = 0; r < 4; ++r) {
          int b = rb + m * 16 + r;
          float v = acc[m][g][r] + bv2;
          if (MODE == MODE_H)
            Hout[(size_t)((lay * 2 + 1) * 256 + b) * 1024 + j2] = f2bf(v);
          else
            outp[(size_t)(lay * 256 + b) * 1024 + j2] = v;
        }
    }
  }
}

// Grid barrier: release fence (wb dirty h/c lines, no inval -> cached lines
// survive) + two-level counter/flag; 4 groups of 49. No acquire fence
// (h-state is read via device-coherent loads).
DEVINL void grid_barrier(u32* bar, int bid, int ep) {
  __syncthreads();
  if (threadIdx.x == 0) {
    __builtin_amdgcn_fence(__ATOMIC_RELEASE, "agent");  // wb dirty lines
    __hip_atomic_fetch_add(bar + (bid & 3) * 64, 1u, __ATOMIC_RELAXED,
                           __HIP_MEMORY_SCOPE_AGENT);
    if (bid == 0) {
#pragma unroll 1
      for (int g = 0; g < 4; ++g)
        while (__hip_atomic_load(bar + g * 64, __ATOMIC_RELAXED,
                                 __HIP_MEMORY_SCOPE_AGENT) < (u32)ep * 49u)
          __builtin_amdgcn_s_sleep(8);
      __hip_atomic_store(bar + 512, (u32)ep, __ATOMIC_RELAXED,
                         __HIP_MEMORY_SCOPE_AGENT);
    } else {
#pragma unroll 1
      while (__hip_atomic_load(bar + 512, __ATOMIC_RELAXED,
                               __HIP_MEMORY_SCOPE_AGENT) < (u32)ep)
        __builtin_amdgcn_s_sleep(8);
    }
  }
  __syncthreads();
}

// Persistent pipelined kernel, PLAIN launch; 196 blocks <= 256 CUs, 96KB LDS
// -> 1 block/CU, all co-resident, software barrier safe.
// jobs 0..2: 64 blocks each (32 bn-stripes of 128 cols x 2 M-halves);
// fc: 4. bid&7 ~ XCD affinity (bn>>2 == bid&7); barrier groups bid&3 (49).
__global__ __launch_bounds__(512, 2) void persist_kernel(Params p, u32* bar) {
  __shared__ u16 Al[3 * SLOT];  // 48KB
  __shared__ u16 Bl[3 * SLOT];  // 48KB
  const int bid = blockIdx.x;
  int job, mb, bn;
  if (bid < 192) {
    job = bid >> 6;
    int r = bid & 63;
    bn = (r & 7) * 4 + (r >> 4);  // 0..31; bn>>2 == bid&7 (XCD-affine)
    mb = (r >> 3) & 1;
  } else {
    job = 3;
    int r = bid - 192;
    mb = r >> 1;
    bn = r & 1;
  }
  u16* HB = p.HB;
#define HBP(lay, pp) (HB + (size_t)(((lay)*2 + (pp)) << 18))
  for (int i = 0; i <= 130; ++i) {
    int t = i - job;
    if ((unsigned)t < 128u) {
      int par = t & 1, pv = par ^ 1;
      if (job == 0) {
        mm_body<MODE_L0>(Al, Bl, HBP(0, pv), nullptr, 1024, 1 << 30, 1024,
                         p.WT0, mb * 128, bn, t, p.G0P, nullptr, p.CC,
                         HBP(0, par), nullptr);
      } else if (job == 1) {
        mm_body<MODE_L>(Al, Bl, HBP(0, par), HBP(1, pv), 1024, 1024, 2048,
                        p.WT1, mb * 128, bn, t, nullptr, p.B1P,
                        p.CC + (size_t)256 * 1024, HBP(1, par), nullptr);
      } else if (job == 2) {
        mm_body<MODE_L>(Al, Bl, HBP(1, par), HBP(2, pv), 1024, 1024, 2048,
                        p.WT2, mb * 128, bn, t, nullptr, p.B2P,
                        p.CC + (size_t)512 * 1024, HBP(2, par), nullptr);
      } else {
        mm_body<MODE_FC>(Al, Bl, HBP(2, par), nullptr, 1024, 1 << 30, 1024,
                         p.FCW, mb * 128, bn, t, nullptr, p.fc_b, nullptr,
                         nullptr, p.out);
      }
    }
    if (i < 130) grid_barrier(bar, bid, i + 1);
  }
#undef HBP
}

// one-time: G0 = x_in@W_ih0+biases (permuted), h/c init = frame@in{h,c}_W + b
// 160 blocks: G0 64 (2 mb x 32 bn), H 48 (2 mb x 24 bn), C 48.
__global__ __launch_bounds__(512, 2) void setup_mm(Params p) {
  __shared__ u16 Al[3 * SLOT];
  __shared__ u16 Bl[3 * SLOT];
  int bid = blockIdx.x;
  if (bid < 64) {
    mm_body<MODE_G0>(Al, Bl, p.FRB, nullptr, 256, 1 << 30, 256, p.WT00,
                     (bid >> 5) * 128, bid & 31, 0, nullptr, p.G0B, nullptr,
                     p.G0P, nullptr);
  } else if (bid < 112) {
    int r = bid - 64;
    mm_body<MODE_H>(Al, Bl, p.FRB, nullptr, 256, 1 << 30, 256, p.WIH,
                    (r / 24) * 128, r % 24, 0, nullptr, p.inh_b, nullptr,
                    p.HB, nullptr);
  } else {
    int r = bid - 112;
    mm_body<MODE_C>(Al, Bl, p.FRB, nullptr, 256, 1 << 30, 256, p.WIC,
                    (r / 24) * 128, r % 24, 0, nullptr, p.inc_b, nullptr,
                    nullptr, p.CC);
  }
}

// fp32 [K][N] sources -> bf16 transposed dst [Nout][Ktot] (K contiguous),
// optional gate permutation of output cols, zero pad k>=Kvalid / n>=Nvalid.
__global__ __launch_bounds__(256) void transpose_bf16(
    const float* __restrict__ srcA, const float* __restrict__ srcB,
    int srcStride, int kSplit, int Kvalid, int Nvalid, int perm,
    u16* __restrict__ dst, int Ktot) {
  __shared__ float tile[64][17];
  int P0 = blockIdx.x * 16;
  int k0 = blockIdx.y * 64;
  int t = threadIdx.x;
  int nl = t & 15;
  int kh = t >> 4;
  int P = P0 + nl;
  int n = perm ? permcol(P) : P;
  bool nok = (n < Nvalid);
#pragma unroll
  for (int q = 0; q < 4; ++q) {
    int kl = q * 16 + kh;
    int k = k0 + kl;
    float v = 0.f;
    if (nok && k < Kvalid) {
      const float* s = (k < kSplit) ? (srcA + (size_t)k * srcStride)
                                    : (srcB + (size_t)(k - kSplit) * srcStride);
      v = s[n];
    }
    tile[kl][nl] = v;
  }
  __syncthreads();
  int jo = t >> 4;
  int kb = (t & 15) << 2;
  u64 pk = (u64)f2bf(tile[kb + 0][jo]) | ((u64)f2bf(tile[kb + 1][jo]) << 16) |
           ((u64)f2bf(tile[kb + 2][jo]) << 32) |
           ((u64)f2bf(tile[kb + 3][jo]) << 48);
  *(u64*)(dst + (size_t)(P0 + jo) * Ktot + k0 + kb) = pk;
}

__global__ __launch_bounds__(256) void build_frame(const float* __restrict__ inputs,
                                                   u16* __restrict__ FRB) {
  int id = blockIdx.x * 256 + threadIdx.x;  // 256*256
  int b = id >> 8, k = id & 255;
  FRB[id] = (k < 204) ? f2bf(inputs[b * 204 + k]) : (u16)0;
}

// G0 bias incl. one-hot label row; layer1/2 combined biases (permuted cols)
__global__ __launch_bounds__(256) void build_bias(
    const float* __restrict__ W_ih0, const float* __restrict__ b_ih0,
    const float* __restrict__ b_hh0, const float* __restrict__ b_ih1,
    const float* __restrict__ b_hh1, const float* __restrict__ b_ih2,
    const float* __restrict__ b_hh2, const int* __restrict__ labels,
    float* __restrict__ G0B, float* __restrict__ B1P, float* __restrict__ B2P) {
  int P = blockIdx.x * 256 + threadIdx.x;  // 4096
  int n = permcol(P);
  int lab = labels[0];
  G0B[P] = W_ih0[(size_t)(204 + lab) * 4096 + n] + b_ih0[n] + b_hh0[n];
  B1P[P] = b_ih1[n] + b_hh1[n];
  B2P[P] = b_ih2[n] + b_hh2[n];
}

extern "C" void kernel_launch(void* const* d_in, const int* in_sizes, int n_in,
                              void* d_out, int out_size, void* d_ws,
                              size_t ws_size, hipStream_t stream) {
  const float* inputs = (const float*)d_in[0];
  const float* W_ih0 = (const float*)d_in[1];
  const float* W_hh0 = (const float*)d_in[2];
  const float* b_ih0 = (const float*)d_in[3];
  const float* b_hh0 = (const float*)d_in[4];
  const float* W_ih1 = (const float*)d_in[5];
  const float* W_hh1 = (const float*)d_in[6];
  const float* b_ih1 = (const float*)d_in[7];
  const float* b_hh1 = (const float*)d_in[8];
  const float* W_ih2 = (const float*)d_in[9];
  const float* W_hh2 = (const float*)d_in[10];
  const float* b_ih2 = (const float*)d_in[11];
  const float* b_hh2 = (const float*)d_in[12];
  const float* fc_W = (const float*)d_in[13];
  const float* fc_b = (const float*)d_in[14];
  const float* inh_W = (const float*)d_in[15];
  const float* inh_b = (const float*)d_in[16];
  const float* inc_W = (const float*)d_in[17];
  const float* inc_b = (const float*)d_in[18];
  const int* labels = (const int*)d_in[19];

  char* ws = (char*)d_ws;
  size_t off = 0;
  auto alloc = [&](size_t bytes) {
    void* r = ws + off;
    off = (off + bytes + 255) & ~(size_t)255;
    return r;
  };
  u16* WT0 = (u16*)alloc(4096ull * 1024 * 2);
  u16* WT1 = (u16*)alloc(4096ull * 2048 * 2);
  u16* WT2 = (u16*)alloc(4096ull * 2048 * 2);
  u16* WT00 = (u16*)alloc(4096ull * 256 * 2);
  u16* FCW = (u16*)alloc(256ull * 1024 * 2);
  u16* WIH = (u16*)alloc(3072ull * 256 * 2);
  u16* WIC = (u16*)alloc(3072ull * 256 * 2);
  u16* FRB = (u16*)alloc(256ull * 256 * 2);
  u16* HB = (u16*)alloc(3ull * 2 * 256 * 1024 * 2);
  u16* G0P = (u16*)alloc(256ull * 4096 * 2);
  float* G0B = (float*)alloc(4096ull * 4);
  float* B1P = (float*)alloc(4096ull * 4);
  float* B2P = (float*)alloc(4096ull * 4);
  float* CC = (float*)alloc(3ull * 256 * 1024 * 4);
  u32* BAR = (u32*)alloc(4096);  // 4 group counters (64-u32 apart) + flag @512
  if (off > ws_size) return;  // workspace too small: fail loudly (validation)

  const int BIG = 1 << 30;
  // weight repack (one-time per call)
  transpose_bf16<<<dim3(256, 16), 256, 0, stream>>>(W_hh0, nullptr, 4096, BIG, 1024, 4096, 1, WT0, 1024);
  transpose_bf16<<<dim3(256, 32), 256, 0, stream>>>(W_ih1, W_hh1, 4096, 1024, 2048, 4096, 1, WT1, 2048);
  transpose_bf16<<<dim3(256, 32), 256, 0, stream>>>(W_ih2, W_hh2, 4096, 1024, 2048, 4096, 1, WT2, 2048);
  transpose_bf16<<<dim3(256, 4), 256, 0, stream>>>(W_ih0, nullptr, 4096, BIG, 204, 4096, 1, WT00, 256);
  transpose_bf16<<<dim3(16, 16), 256, 0, stream>>>(fc_W, nullptr, 204, BIG, 1024, 204, 0, FCW, 1024);
  transpose_bf16<<<dim3(192, 4), 256, 0, stream>>>(inh_W, nullptr, 3072, BIG, 204, 3072, 0, WIH, 256);
  transpose_bf16<<<dim3(192, 4), 256, 0, stream>>>(inc_W, nullptr, 3072, BIG, 204, 3072, 0, WIC, 256);
  build_frame<<<256, 256, 0, stream>>>(inputs, FRB);
  build_bias<<<16, 256, 0, stream>>>(W_ih0, b_ih0, b_hh0, b_ih1, b_hh1, b_ih2,
                                     b_hh2, labels, G0B, B1P, B2P);
  hipMemsetAsync(BAR, 0, 4096, stream);

  Params p;
  p.fc_b = fc_b; p.inh_b = inh_b; p.inc_b = inc_b;
  p.WT0 = WT0; p.WT1 = WT1; p.WT2 = WT2; p.WT00 = WT00; p.FCW = FCW;
  p.WIH = WIH; p.WIC = WIC; p.FRB = FRB; p.HB = HB;
  p.G0P = G0P; p.G0B = G0B; p.B1P = B1P; p.B2P = B2P; p.CC = CC;
  p.out = (float*)d_out;

  setup_mm<<<160, 512, 0, stream>>>(p);

  // persistent pipelined sequence: one plain launch, software grid barrier
  persist_kernel<<<196, 512, 0, stream>>>(p, BAR);
}

// Round 15
// 4299.234 us; speedup vs baseline: 1.4225x; 1.2756x over previous
//
#include <hip/hip_runtime.h>

// DecoderRNN: 3-layer LSTM (H=1024) + fc, B=256, 128 steps, constant input.
// bf16 MFMA 16x16x32; gate-interleaved weight columns; persistent plain-launch
// kernel with software grid barrier; h-state via device-coherent loads.
// Base = R8 structure (best: 40us/step, fabric-saturated at 242 MB/step).
// THIS ROUND: leader-only release fence. XCD census (XCC_ID, R9-proven);
// per step each block arrives at its XCD counter; the XCD's rank-0 leader
// alone waits + issues ONE fence(release)=buffer_wbl2 (flushes the whole
// XCD L2 incl. other blocks' dirty h) + arrives globally; root polls 8
// counters with 8 parallel lanes; flag releases everyone.
// wbl2 ops/step: 392 -> 8 (kills the suspected fence storm).

#define DEVINL static __device__ __forceinline__

typedef __bf16 bf16x8 __attribute__((ext_vector_type(8)));
typedef float f32x4 __attribute__((ext_vector_type(4)));
typedef unsigned short u16;
typedef unsigned int u32;
typedef unsigned long long u64;

DEVINL u16 f2bf(float f) {
  u32 u = __builtin_bit_cast(u32, f);
  u += 0x7fffu + ((u >> 16) & 1u);  // RNE
  return (u16)(u >> 16);
}
DEVINL float bf2f(u16 h) {
  u32 u = (u32)h << 16;
  return __builtin_bit_cast(float, u);
}
DEVINL float sigm(float x) { return 1.0f / (1.0f + __expf(-x)); }
DEVINL float tanhfast(float x) { return 1.0f - 2.0f / (1.0f + __expf(2.0f * x)); }

// device-coherent global->LDS (h-state: written by other XCDs) [R8-proven]
DEVINL void glds_coh(const u16* g, u16* l) {
  __builtin_amdgcn_global_load_lds(
      (const __attribute__((address_space(1))) u32*)g,
      (__attribute__((address_space(3))) u32*)l, 16, 0, 17);  // sc0|sc1
}
// cached global->LDS (weights: read-only)
DEVINL void glds_w(const u16* g, u16* l) {
  __builtin_amdgcn_global_load_lds(
      (const __attribute__((address_space(1))) u32*)g,
      (__attribute__((address_space(3))) u32*)l, 16, 0, 0);
}

// permuted column index -> original gate column: P = grp*64 + g*16 + jj
DEVINL int permcol(int P) {
  int grp = P >> 6, g = (P >> 4) & 3, jj = P & 15;
  return g * 1024 + grp * 16 + jj;
}

struct Params {
  const float* fc_b;
  const float* inh_b;
  const float* inc_b;
  const u16 *WT0, *WT1, *WT2, *WT00, *FCW, *WIH, *WIC, *FRB;
  u16* HB;   // h state bf16: [layer][parity][256][1024]  (1<<18 u16 per buf)
  u16* G0P;  // precomputed layer0 input gates, bf16 [256][4096]
  float *G0B, *B1P, *B2P, *CC;  // CC: c state fp32 [layer][256][1024]
  float* out;
};

#define MODE_L0 0
#define MODE_L 1
#define MODE_FC 2
#define MODE_G0 3
#define MODE_H 4
#define MODE_C 5

// one 64-K tile: per thread 4 A-loads (coherent) + 2 B-loads (cached),
// direct to LDS. Source-side XOR swizzle (granule ^ row&7); LDS dest linear.
DEVINL void issue_tile(int kt, const u16* A0, const u16* A1, int kSplit, int sA,
                       int K, const u16* Wt, int m0, int wrow,
                       const int (&rq)[4], const int (&kqs)[4],
                       const int (&lo)[4], u16* Abuf, u16* Bbuf) {
  const u16* Ab = (kt < kSplit) ? (A0 + kt) : (A1 + (kt - kSplit));
#pragma unroll
  for (int q = 0; q < 4; ++q)
    glds_coh(Ab + (size_t)(m0 + rq[q]) * sA + kqs[q] * 8, Abuf + lo[q]);
  const u16* Bb = Wt + kt;
#pragma unroll
  for (int q = 0; q < 2; ++q)
    glds_w(Bb + (size_t)(wrow + rq[q]) * K + kqs[q] * 8, Bbuf + lo[q]);
}

DEVINL void mfma_tile(const u16* Al, const u16* Bl, f32x4 (&acc)[2][4], int rl0,
                      int hh, int e7, int jj) {
#pragma unroll
  for (int kk = 0; kk < 2; ++kk) {
    int sl = (((kk << 2) | hh) ^ e7) * 8;
    bf16x8 a0 = *(const bf16x8*)(Al + rl0 * 64 + sl);
    bf16x8 a1 = *(const bf16x8*)(Al + (rl0 + 16) * 64 + sl);
    bf16x8 b0 = *(const bf16x8*)(Bl + (jj)*64 + sl);
    bf16x8 b1 = *(const bf16x8*)(Bl + (16 + jj) * 64 + sl);
    bf16x8 b2 = *(const bf16x8*)(Bl + (32 + jj) * 64 + sl);
    bf16x8 b3 = *(const bf16x8*)(Bl + (48 + jj) * 64 + sl);
    acc[0][0] = __builtin_amdgcn_mfma_f32_16x16x32_bf16(a0, b0, acc[0][0], 0, 0, 0);
    acc[0][1] = __builtin_amdgcn_mfma_f32_16x16x32_bf16(a0, b1, acc[0][1], 0, 0, 0);
    acc[0][2] = __builtin_amdgcn_mfma_f32_16x16x32_bf16(a0, b2, acc[0][2], 0, 0, 0);
    acc[0][3] = __builtin_amdgcn_mfma_f32_16x16x32_bf16(a0, b3, acc[0][3], 0, 0, 0);
    acc[1][0] = __builtin_amdgcn_mfma_f32_16x16x32_bf16(a1, b0, acc[1][0], 0, 0, 0);
    acc[1][1] = __builtin_amdgcn_mfma_f32_16x16x32_bf16(a1, b1, acc[1][1], 0, 0, 0);
    acc[1][2] = __builtin_amdgcn_mfma_f32_16x16x32_bf16(a1, b2, acc[1][2], 0, 0, 0);
    acc[1][3] = __builtin_amdgcn_mfma_f32_16x16x32_bf16(a1, b3, acc[1][3], 0, 0, 0);
  }
}

// Block: 256 threads = 4 waves, output tile 128(M) x 64(N); wave w = rows
// [w*32, w*32+32): 2 M-frags x 4 N-frags. LDS double-buffered.
// Counted vmcnt(6): next tile's 6 loads stay in flight across both barriers.
template <int MODE>
DEVINL void mm_body(u16* Al, u16* Bl, const u16* A0, const u16* A1, int sA,
                    int kSplit, int K, const u16* Wt, int m0, int bn, int t,
                    const u16* Gfull, const float* biasP, float* Cst, u16* Hout,
                    float* outp) {
  const int tid = threadIdx.x;
  const int l = tid & 63;
  const int w = tid >> 6;
  const int hh = (l >> 4) & 3;
  const int jj = l & 15;
  const int rl0 = w * 32 + jj;
  const int e7 = l & 7;

  int rq[4], kqs[4], lo[4];
#pragma unroll
  for (int q = 0; q < 4; ++q) {
    int L = tid + q * 256;
    rq[q] = L >> 3;
    kqs[q] = (L & 7) ^ (rq[q] & 7);       // source-swizzled granule
    lo[q] = ((tid & ~63) + q * 256) * 8;  // wave-uniform LDS base (u16 units)
  }

  f32x4 acc[2][4];
#pragma unroll
  for (int m = 0; m < 2; ++m)
#pragma unroll
    for (int g = 0; g < 4; ++g) acc[m][g] = (f32x4){0.f, 0.f, 0.f, 0.f};

  const int wrow = bn * 64;
  const int n = K >> 6;  // 64-K tiles

  issue_tile(0, A0, A1, kSplit, sA, K, Wt, m0, wrow, rq, kqs, lo, Al, Bl);
  issue_tile(64, A0, A1, kSplit, sA, K, Wt, m0, wrow, rq, kqs, lo, Al + 8192,
             Bl + 4096);

  for (int j = 0; j < n; ++j) {
    u16* Ac = Al + (j & 1) * 8192;
    u16* Bc = Bl + (j & 1) * 4096;
    if (j < n - 1)
      asm volatile("s_waitcnt vmcnt(6)" ::: "memory");
    else
      asm volatile("s_waitcnt vmcnt(0)" ::: "memory");
    __builtin_amdgcn_s_barrier();
    __builtin_amdgcn_sched_barrier(0);
    mfma_tile(Ac, Bc, acc, rl0, hh, e7, jj);
    __builtin_amdgcn_sched_barrier(0);
    __builtin_amdgcn_s_barrier();
    if (j + 2 < n)
      issue_tile((j + 2) * 64, A0, A1, kSplit, sA, K, Wt, m0, wrow, rq, kqs, lo,
                 Ac, Bc);
  }

  // C/D layout: col = lane&15, row = (lane>>4)*4 + reg  [m89-verified]
  const int rb = m0 + w * 32 + (hh << 2);
  if (MODE <= MODE_L) {
    float add0 = 0.f, add1 = 0.f, add2 = 0.f, add3 = 0.f;
    if (MODE == MODE_L) {
      add0 = biasP[bn * 64 + jj];
      add1 = biasP[bn * 64 + 16 + jj];
      add2 = biasP[bn * 64 + 32 + jj];
      add3 = biasP[bn * 64 + 48 + jj];
    }
    const int j = bn * 16 + jj;  // hidden unit
#pragma unroll
    for (int m = 0; m < 2; ++m) {
#pragma unroll
      for (int r = 0; r < 4; ++r) {
        int b = rb + m * 16 + r;
        float g0v, g1v, g2v, g3v;
        if (MODE == MODE_L0) {
          const u16* G = Gfull + (size_t)b * 4096 + bn * 64 + jj;
          g0v = acc[m][0][r] + bf2f(G[0]);
          g1v = acc[m][1][r] + bf2f(G[16]);
          g2v = acc[m][2][r] + bf2f(G[32]);
          g3v = acc[m][3][r] + bf2f(G[48]);
        } else {
          g0v = acc[m][0][r] + add0;
          g1v = acc[m][1][r] + add1;
          g2v = acc[m][2][r] + add2;
          g3v = acc[m][3][r] + add3;
        }
        float iv = sigm(g0v), fv = sigm(g1v), gv = tanhfast(g2v), ov = sigm(g3v);
        size_t ci = (size_t)b * 1024 + j;
        float cn = fv * Cst[ci] + iv * gv;
        Cst[ci] = cn;
        Hout[ci] = f2bf(ov * tanhfast(cn));
      }
    }
  } else if (MODE == MODE_FC) {
#pragma unroll
    for (int g = 0; g < 4; ++g) {
      int nn = bn * 64 + g * 16 + jj;
      if (nn < 204) {
        float bv2 = biasP[nn];
#pragma unroll
        for (int m = 0; m < 2; ++m)
#pragma unroll
          for (int r = 0; r < 4; ++r) {
            int b = rb + m * 16 + r;
            outp[((size_t)b * 128 + t) * 204 + nn] = acc[m][g][r] + bv2;
          }
      }
    }
  } else if (MODE == MODE_G0) {
#pragma unroll
    for (int g = 0; g < 4; ++g) {
      int P = bn * 64 + g * 16 + jj;
      float bv2 = biasP[P];
#pragma unroll
      for (int m = 0; m < 2; ++m)
#pragma unroll
        for (int r = 0; r < 4; ++r) {
          int b = rb + m * 16 + r;
          Hout[(size_t)b * 4096 + P] = f2bf(acc[m][g][r] + bv2);
        }
    }
  } else {  // MODE_H / MODE_C : init states, cols are orig n = lay*1024 + j
#pragma unroll
    for (int g = 0; g < 4; ++g) {
      int nn = bn * 64 + g * 16 + jj;
      int lay = nn >> 10, j2 = nn & 1023;
      float bv2 = biasP[nn];
#pragma unroll
      for (int m = 0; m < 2; ++m)
#pragma unroll
        for (int r = 0; r < 4; ++r) {
          int b = rb + m * 16 + r;
          float v = acc[m][g][r] + bv2;
          if (MODE == MODE_H)
            Hout[(size_t)((lay * 2 + 1) * 256 + b) * 1024 + j2] = f2bf(v);
          else
            outp[(size_t)(lay * 256 + b) * 1024 + j2] = v;
        }
    }
  }
}

// BAR layout (u32 idx): per-XCD global arrive x*64 (x<8); flag @512;
// census one-shot counter @768; census counts @1024+x*64; per-XCD step
// counters @2048+x*64.  (16 KB total, memset to 0 each call.)

// Step barrier with leader-only release fence.
// All blocks: drain stores to L2 (__syncthreads emits vmcnt(0)), arrive at
// their XCD counter. XCD leader (rank 0): wait for all nb same-XCD arrivals,
// ONE fence(release, agent) [buffer_wbl2: flushes every dirty line in this
// XCD's L2, incl. other blocks' h], then arrive globally. Root block: poll
// the (up to) 8 global arrivals with parallel lanes, set flag. Others: poll
// flag. Consumers then read h via MALL-coherent loads (fresh by the chain:
// stores->L2 -> leader wbl2 -> MALL -> arrive -> flag -> consumer load).
DEVINL void step_barrier(u32* bar, int bid, int x, int rank, int nb, int ep) {
  __syncthreads();  // drains this block's stores into L2
  const int tid = threadIdx.x;
  if (tid == 0) {
    __hip_atomic_fetch_add(bar + 2048 + x * 64, 1u, __ATOMIC_RELAXED,
                           __HIP_MEMORY_SCOPE_AGENT);
    if (rank == 0) {
#pragma unroll 1
      while (__hip_atomic_load(bar + 2048 + x * 64, __ATOMIC_RELAXED,
                               __HIP_MEMORY_SCOPE_AGENT) < (u32)ep * (u32)nb)
        __builtin_amdgcn_s_sleep(4);
      __builtin_amdgcn_fence(__ATOMIC_RELEASE, "agent");  // 1 wbl2 / XCD
      __hip_atomic_fetch_add(bar + x * 64, 1u, __ATOMIC_RELAXED,
                             __HIP_MEMORY_SCOPE_AGENT);
    }
  }
  if (bid == 0) {
    if (tid < 8) {
      u32 cnt = __hip_atomic_load(bar + 1024 + tid * 64, __ATOMIC_RELAXED,
                                  __HIP_MEMORY_SCOPE_AGENT);
      if (cnt > 0) {
#pragma unroll 1
        while (__hip_atomic_load(bar + tid * 64, __ATOMIC_RELAXED,
                                 __HIP_MEMORY_SCOPE_AGENT) < (u32)ep)
          __builtin_amdgcn_s_sleep(4);
      }
    }
    __syncthreads();  // all 8 poll lanes done
    if (tid == 0)
      __hip_atomic_store(bar + 512, (u32)ep, __ATOMIC_RELAXED,
                         __HIP_MEMORY_SCOPE_AGENT);
  } else if (tid == 0) {
#pragma unroll 1
    while (__hip_atomic_load(bar + 512, __ATOMIC_RELAXED,
                             __HIP_MEMORY_SCOPE_AGENT) < (u32)ep)
      __builtin_amdgcn_s_sleep(8);
  }
  __syncthreads();
}

// Persistent pipelined kernel, PLAIN launch; 392 blocks co-resident:
// LDS 48KB -> 3 blocks/CU; launch_bounds(256,2) -> VGPR<=128 -> >=2/CU;
// 392 <= 512. bid&7 ~ XCD affinity (bn>>3 == bid&7).
__global__ __launch_bounds__(256, 2) void persist_kernel(Params p, u32* bar) {
  __shared__ u16 Al[2 * 128 * 64];  // 32KB
  __shared__ u16 Bl[2 * 64 * 64];   // 16KB
  __shared__ int sh_x, sh_rank, sh_nb;
  const int bid = blockIdx.x;
  int job, mb, bn;
  if (bid < 384) {
    job = bid >> 7;
    int r = bid & 127;
    bn = (r & 7) * 8 + (r >> 4);  // bn>>3 == bid&7 (XCD-affine weight slice)
    mb = (r >> 3) & 1;
  } else {
    job = 3;
    int r = bid - 384;
    mb = r >> 2;
    bn = r & 3;
  }

  // ---- XCD census (R9-proven: physical XCD id + per-XCD rank) ----
  if (threadIdx.x == 0) {
    int x = __builtin_amdgcn_s_getreg((31 << 11) | 20) & 7;  // HW_REG_XCC_ID
    sh_x = x;
    sh_rank = (int)__hip_atomic_fetch_add(bar + 1024 + x * 64, 1u,
                                          __ATOMIC_RELAXED,
                                          __HIP_MEMORY_SCOPE_AGENT);
  }
  __syncthreads();
  const int x = sh_x, rank = sh_rank;
  if (threadIdx.x == 0) {  // census complete barrier (one-shot, 392 arrivals)
    __hip_atomic_fetch_add(bar + 768, 1u, __ATOMIC_RELAXED,
                           __HIP_MEMORY_SCOPE_AGENT);
#pragma unroll 1
    while (__hip_atomic_load(bar + 768, __ATOMIC_RELAXED,
                             __HIP_MEMORY_SCOPE_AGENT) < 392u)
      __builtin_amdgcn_s_sleep(8);
    sh_nb = (int)__hip_atomic_load(bar + 1024 + x * 64, __ATOMIC_RELAXED,
                                   __HIP_MEMORY_SCOPE_AGENT);
  }
  __syncthreads();
  const int nb = sh_nb;

  u16* HB = p.HB;
#define HBP(lay, pp) (HB + (size_t)(((lay)*2 + (pp)) << 18))
  for (int i = 0; i <= 130; ++i) {
    int t = i - job;
    if ((unsigned)t < 128u) {
      int par = t & 1, pv = par ^ 1;
      if (job == 0) {
        mm_body<MODE_L0>(Al, Bl, HBP(0, pv), nullptr, 1024, 1 << 30, 1024,
                         p.WT0, mb * 128, bn, t, p.G0P, nullptr, p.CC,
                         HBP(0, par), nullptr);
      } else if (job == 1) {
        mm_body<MODE_L>(Al, Bl, HBP(0, par), HBP(1, pv), 1024, 1024, 2048,
                        p.WT1, mb * 128, bn, t, nullptr, p.B1P,
                        p.CC + (size_t)256 * 1024, HBP(1, par), nullptr);
      } else if (job == 2) {
        mm_body<MODE_L>(Al, Bl, HBP(1, par), HBP(2, pv), 1024, 1024, 2048,
                        p.WT2, mb * 128, bn, t, nullptr, p.B2P,
                        p.CC + (size_t)512 * 1024, HBP(2, par), nullptr);
      } else {
        mm_body<MODE_FC>(Al, Bl, HBP(2, par), nullptr, 1024, 1 << 30, 1024,
                         p.FCW, mb * 128, bn, t, nullptr, p.fc_b, nullptr,
                         nullptr, p.out);
      }
    }
    if (i < 130) step_barrier(bar, bid, x, rank, nb, i + 1);
  }
#undef HBP
}

// one-time: G0 = x_in@W_ih0+biases (permuted), h/c init = frame@in{h,c}_W + b
__global__ __launch_bounds__(256, 2) void setup_mm(Params p) {
  __shared__ u16 Al[2 * 128 * 64];
  __shared__ u16 Bl[2 * 64 * 64];
  int bid = blockIdx.x;
  if (bid < 128) {
    mm_body<MODE_G0>(Al, Bl, p.FRB, nullptr, 256, 1 << 30, 256, p.WT00,
                     (bid >> 6) * 128, bid & 63, 0, nullptr, p.G0B, nullptr,
                     p.G0P, nullptr);
  } else if (bid < 224) {
    int b2 = bid - 128;
    mm_body<MODE_H>(Al, Bl, p.FRB, nullptr, 256, 1 << 30, 256, p.WIH,
                    (b2 / 48) * 128, b2 % 48, 0, nullptr, p.inh_b, nullptr,
                    p.HB, nullptr);
  } else {
    int b2 = bid - 224;
    mm_body<MODE_C>(Al, Bl, p.FRB, nullptr, 256, 1 << 30, 256, p.WIC,
                    (b2 / 48) * 128, b2 % 48, 0, nullptr, p.inc_b, nullptr,
                    nullptr, p.CC);
  }
}

// fp32 [K][N] sources -> bf16 transposed dst [Nout][Ktot] (K contiguous),
// optional gate permutation of output cols, zero pad k>=Kvalid / n>=Nvalid.
__global__ __launch_bounds__(256) void transpose_bf16(
    const float* __restrict__ srcA, const float* __restrict__ srcB,
    int srcStride, int kSplit, int Kvalid, int Nvalid, int perm,
    u16* __restrict__ dst, int Ktot) {
  __shared__ float tile[64][17];
  int P0 = blockIdx.x * 16;
  int k0 = blockIdx.y * 64;
  int t = threadIdx.x;
  int nl = t & 15;
  int kh = t >> 4;
  int P = P0 + nl;
  int n = perm ? permcol(P) : P;
  bool nok = (n < Nvalid);
#pragma unroll
  for (int q = 0; q < 4; ++q) {
    int kl = q * 16 + kh;
    int k = k0 + kl;
    float v = 0.f;
    if (nok && k < Kvalid) {
      const float* s = (k < kSplit) ? (srcA + (size_t)k * srcStride)
                                    : (srcB + (size_t)(k - kSplit) * srcStride);
      v = s[n];
    }
    tile[kl][nl] = v;
  }
  __syncthreads();
  int jo = t >> 4;
  int kb = (t & 15) << 2;
  u64 pk = (u64)f2bf(tile[kb + 0][jo]) | ((u64)f2bf(tile[kb + 1][jo]) << 16) |
           ((u64)f2bf(tile[kb + 2][jo]) << 32) |
           ((u64)f2bf(tile[kb + 3][jo]) << 48);
  *(u64*)(dst + (size_t)(P0 + jo) * Ktot + k0 + kb) = pk;
}

__global__ __launch_bounds__(256) void build_frame(const float* __restrict__ inputs,
                                                   u16* __restrict__ FRB) {
  int id = blockIdx.x * 256 + threadIdx.x;  // 256*256
  int b = id >> 8, k = id & 255;
  FRB[id] = (k < 204) ? f2bf(inputs[b * 204 + k]) : (u16)0;
}

// G0 bias incl. one-hot label row; layer1/2 combined biases (permuted cols)
__global__ __launch_bounds__(256) void build_bias(
    const float* __restrict__ W_ih0, const float* __restrict__ b_ih0,
    const float* __restrict__ b_hh0, const float* __restrict__ b_ih1,
    const float* __restrict__ b_hh1, const float* __restrict__ b_ih2,
    const float* __restrict__ b_hh2, const int* __restrict__ labels,
    float* __restrict__ G0B, float* __restrict__ B1P, float* __restrict__ B2P) {
  int P = blockIdx.x * 256 + threadIdx.x;  // 4096
  int n = permcol(P);
  int lab = labels[0];
  G0B[P] = W_ih0[(size_t)(204 + lab) * 4096 + n] + b_ih0[n] + b_hh0[n];
  B1P[P] = b_ih1[n] + b_hh1[n];
  B2P[P] = b_ih2[n] + b_hh2[n];
}

extern "C" void kernel_launch(void* const* d_in, const int* in_sizes, int n_in,
                              void* d_out, int out_size, void* d_ws,
                              size_t ws_size, hipStream_t stream) {
  const float* inputs = (const float*)d_in[0];
  const float* W_ih0 = (const float*)d_in[1];
  const float* W_hh0 = (const float*)d_in[2];
  const float* b_ih0 = (const float*)d_in[3];
  const float* b_hh0 = (const float*)d_in[4];
  const float* W_ih1 = (const float*)d_in[5];
  const float* W_hh1 = (const float*)d_in[6];
  const float* b_ih1 = (const float*)d_in[7];
  const float* b_hh1 = (const float*)d_in[8];
  const float* W_ih2 = (const float*)d_in[9];
  const float* W_hh2 = (const float*)d_in[10];
  const float* b_ih2 = (const float*)d_in[11];
  const float* b_hh2 = (const float*)d_in[12];
  const float* fc_W = (const float*)d_in[13];
  const float* fc_b = (const float*)d_in[14];
  const float* inh_W = (const float*)d_in[15];
  const float* inh_b = (const float*)d_in[16];
  const float* inc_W = (const float*)d_in[17];
  const float* inc_b = (const float*)d_in[18];
  const int* labels = (const int*)d_in[19];

  char* ws = (char*)d_ws;
  size_t off = 0;
  auto alloc = [&](size_t bytes) {
    void* r = ws + off;
    off = (off + bytes + 255) & ~(size_t)255;
    return r;
  };
  u16* WT0 = (u16*)alloc(4096ull * 1024 * 2);
  u16* WT1 = (u16*)alloc(4096ull * 2048 * 2);
  u16* WT2 = (u16*)alloc(4096ull * 2048 * 2);
  u16* WT00 = (u16*)alloc(4096ull * 256 * 2);
  u16* FCW = (u16*)alloc(256ull * 1024 * 2);
  u16* WIH = (u16*)alloc(3072ull * 256 * 2);
  u16* WIC = (u16*)alloc(3072ull * 256 * 2);
  u16* FRB = (u16*)alloc(256ull * 256 * 2);
  u16* HB = (u16*)alloc(3ull * 2 * 256 * 1024 * 2);
  u16* G0P = (u16*)alloc(256ull * 4096 * 2);
  float* G0B = (float*)alloc(4096ull * 4);
  float* B1P = (float*)alloc(4096ull * 4);
  float* B2P = (float*)alloc(4096ull * 4);
  float* CC = (float*)alloc(3ull * 256 * 1024 * 4);
  u32* BAR = (u32*)alloc(16384);  // barrier/census area (see layout comment)
  if (off > ws_size) return;  // workspace too small: fail loudly (validation)

  const int BIG = 1 << 30;
  // weight repack (one-time per call)
  transpose_bf16<<<dim3(256, 16), 256, 0, stream>>>(W_hh0, nullptr, 4096, BIG, 1024, 4096, 1, WT0, 1024);
  transpose_bf16<<<dim3(256, 32), 256, 0, stream>>>(W_ih1, W_hh1, 4096, 1024, 2048, 4096, 1, WT1, 2048);
  transpose_bf16<<<dim3(256, 32), 256, 0, stream>>>(W_ih2, W_hh2, 4096, 1024, 2048, 4096, 1, WT2, 2048);
  transpose_bf16<<<dim3(256, 4), 256, 0, stream>>>(W_ih0, nullptr, 4096, BIG, 204, 4096, 1, WT00, 256);
  transpose_bf16<<<dim3(16, 16), 256, 0, stream>>>(fc_W, nullptr, 204, BIG, 1024, 204, 0, FCW, 1024);
  transpose_bf16<<<dim3(192, 4), 256, 0, stream>>>(inh_W, nullptr, 3072, BIG, 204, 3072, 0, WIH, 256);
  transpose_bf16<<<dim3(192, 4), 256, 0, stream>>>(inc_W, nullptr, 3072, BIG, 204, 3072, 0, WIC, 256);
  build_frame<<<256, 256, 0, stream>>>(inputs, FRB);
  build_bias<<<16, 256, 0, stream>>>(W_ih0, b_ih0, b_hh0, b_ih1, b_hh1, b_ih2,
                                     b_hh2, labels, G0B, B1P, B2P);
  hipMemsetAsync(BAR, 0, 16384, stream);

  Params p;
  p.fc_b = fc_b; p.inh_b = inh_b; p.inc_b = inc_b;
  p.WT0 = WT0; p.WT1 = WT1; p.WT2 = WT2; p.WT00 = WT00; p.FCW = FCW;
  p.WIH = WIH; p.WIC = WIC; p.FRB = FRB; p.HB = HB;
  p.G0P = G0P; p.G0B = G0B; p.B1P = B1P; p.B2P = B2P; p.CC = CC;
  p.out = (float*)d_out;

  setup_mm<<<320, 256, 0, stream>>>(p);

  // persistent pipelined sequence: one plain launch, software grid barrier
  persist_kernel<<<392, 256, 0, stream>>>(p, BAR);
}